// Round 8
// baseline (593.976 us; speedup 1.0000x reference)
//
#include <hip/hip_runtime.h>
#include <hip/hip_bf16.h>
#include <math.h>

typedef __hip_bfloat16 bf16t;
typedef __attribute__((ext_vector_type(8))) short short8;
typedef __attribute__((ext_vector_type(4))) float f32x4;

#define DI 1024
#define NSTATE 16
#define TLEN 2048
#define LOG2E 1.4426950408889634f

__device__ __forceinline__ float b2f(bf16t v) { return __bfloat162float(v); }
__device__ __forceinline__ bf16t f2b(float v) { return __float2bfloat16(v); }
__device__ __forceinline__ float softplusf(float v) { return (v > 20.f) ? v : log1pf(expf(v)); }

// runtime-dtype load for RAW INPUTS: f=1 -> fp32, f=0 -> bf16
__device__ __forceinline__ float load_any(const void* s, long i, int f) {
  return f ? ((const float*)s)[i] : b2f(((const bf16t*)s)[i]);
}

__device__ __forceinline__ void async16(const void* g, void* l) {
  __builtin_amdgcn_global_load_lds(
      (const __attribute__((address_space(1))) unsigned int*)g,
      (__attribute__((address_space(3))) unsigned int*)l, 16, 0, 0);
}

// ---------------- dtype detect: flag=1 if inputs are fp32, 0 if bf16
__global__ __launch_bounds__(256) void detect_dtype(const unsigned int* __restrict__ x,
                                                    int* __restrict__ flag) {
  __shared__ int cnt;
  if (threadIdx.x == 0) cnt = 0;
  __syncthreads();
  unsigned int w = x[threadIdx.x];
  int e = (w >> 7) & 0xFF;
  if (e >= 110 && e <= 135) atomicAdd(&cnt, 1);
  __syncthreads();
  if (threadIdx.x == 0) *flag = (cnt < 128) ? 1 : 0;
}

// ---------------- hi/lo split cast of the 4 GEMM matrices
__global__ __launch_bounds__(256) void cast_hilo(
    const void* __restrict__ x, const void* __restrict__ w1,
    const void* __restrict__ xw, const void* __restrict__ w3,
    short* __restrict__ bigH, short* __restrict__ bigL,
    short* __restrict__ smallH, short* __restrict__ smallL,
    const int* __restrict__ flag) {
  int i = blockIdx.x * 256 + threadIdx.x;   // 0 .. 3735552
  int f = *flag;
  float v; short *dh, *dl; int o;
  if (i < 3145728) {
    v = (i < 2097152) ? load_any(x, i, f) : load_any(w1, i - 2097152, f);
    dh = bigH; dl = bigL; o = i;
  } else {
    int j = i - 3145728;
    v = (j < 65536) ? load_any(xw, j, f) : load_any(w3, j - 65536, f);
    dh = smallH; dl = smallL; o = j;
  }
  bf16t h = f2b(v);
  dh[o] = *(short*)&h;
  bf16t l = f2b(v - b2f(h));
  dl[o] = *(short*)&l;
}

// ---------------- split-bf16 MFMA GEMM: C[M,N] (fp32) = A[M,K] * B[N,K]^T
template <int BM>
__global__ __launch_bounds__(256) void gemm_split(
    const short* __restrict__ Ah, const short* __restrict__ Al,
    const short* __restrict__ Bh, const short* __restrict__ Bl,
    float* __restrict__ C, int K, int lda, int ldb, int ldc)
{
  constexpr int NF = BM / 32;
  __shared__ __align__(16) short lAh[BM * 32], lAl[BM * 32], lBh[BM * 32], lBl[BM * 32];
  int tid = threadIdx.x;
  int lane = tid & 63, wave = tid >> 6;
  int bm = blockIdx.x * BM, bn = blockIdx.y * BM;
  int wm = (wave & 1) * (BM / 2), wn = (wave >> 1) * (BM / 2);
  f32x4 acc[NF][NF] = {};
  int r0 = tid >> 2, kp = (tid & 3) * 8;
  const short* pAh = Ah + (size_t)(bm + r0) * lda + kp;
  const short* pAl = Al + (size_t)(bm + r0) * lda + kp;
  const short* pBh = Bh + (size_t)(bn + r0) * ldb + kp;
  const short* pBl = Bl + (size_t)(bn + r0) * ldb + kp;
  int ldsOff = tid * 8;
  int la = (lane & 15) * 32 + (lane >> 4) * 8;
  for (int kk = 0; kk < K; kk += 32) {
#pragma unroll
    for (int s = 0; s < BM / 64; s++) {
      async16(pAh + kk + (size_t)s * 64 * lda, &lAh[ldsOff + s * 64 * 32]);
      async16(pAl + kk + (size_t)s * 64 * lda, &lAl[ldsOff + s * 64 * 32]);
      async16(pBh + kk + (size_t)s * 64 * ldb, &lBh[ldsOff + s * 64 * 32]);
      async16(pBl + kk + (size_t)s * 64 * ldb, &lBl[ldsOff + s * 64 * 32]);
    }
    asm volatile("s_waitcnt vmcnt(0)" ::: "memory");
    __syncthreads();
    short8 ah[NF], al[NF], bh[NF], bl[NF];
#pragma unroll
    for (int i = 0; i < NF; i++) {
      ah[i] = *(const short8*)&lAh[(wm + i * 16) * 32 + la];
      al[i] = *(const short8*)&lAl[(wm + i * 16) * 32 + la];
      bh[i] = *(const short8*)&lBh[(wn + i * 16) * 32 + la];
      bl[i] = *(const short8*)&lBl[(wn + i * 16) * 32 + la];
    }
#pragma unroll
    for (int i = 0; i < NF; i++)
#pragma unroll
      for (int j = 0; j < NF; j++) {
        acc[i][j] = __builtin_amdgcn_mfma_f32_16x16x32_bf16(ah[i], bh[j], acc[i][j], 0, 0, 0);
        acc[i][j] = __builtin_amdgcn_mfma_f32_16x16x32_bf16(ah[i], bl[j], acc[i][j], 0, 0, 0);
        acc[i][j] = __builtin_amdgcn_mfma_f32_16x16x32_bf16(al[i], bh[j], acc[i][j], 0, 0, 0);
      }
    __syncthreads();
  }
  int rbase = (lane >> 4) * 4, ncol = lane & 15;
#pragma unroll
  for (int i = 0; i < NF; i++)
#pragma unroll
    for (int j = 0; j < NF; j++)
#pragma unroll
      for (int r = 0; r < 4; r++) {
        int m = bm + wm + i * 16 + rbase + r;
        int n = bn + wn + j * 16 + ncol;
        C[(size_t)m * ldc + n] = acc[i][j][r];
      }
}

// ---------------- depthwise causal conv(K=4) + SiLU -> xt as bf16 hi/lo pair
__global__ __launch_bounds__(256) void conv_silu(
    const float* __restrict__ proj, const void* __restrict__ cw,
    const void* __restrict__ cb, short* __restrict__ xh, short* __restrict__ xl,
    const int* __restrict__ flag)
{
  int f = *flag;
  int idx = blockIdx.x * 256 + threadIdx.x;
  int d = idx & (DI - 1);
  int row = idx >> 10;
  int t = row & (TLEN - 1);
  float acc = load_any(cb, d, f);
#pragma unroll
  for (int k = 0; k < 4; k++) {
    int ts = t - 3 + k;
    if (ts >= 0) acc += load_any(cw, d * 4 + k, f) * proj[(size_t)(row - 3 + k) * 2048 + d];
  }
  float s = acc / (1.f + expf(-acc));
  bf16t h = f2b(s);
  xh[idx] = *(short*)&h;
  bf16t l = f2b(s - b2f(h));
  xl[idx] = *(short*)&l;
}

// ---------------- dt precompute: dtf[row,d] = softplus(ssm[row,0:32] . dtw[d,:] + dtb[d])
__global__ __launch_bounds__(256) void dt_kernel(
    const float* __restrict__ ssm, const void* __restrict__ dtw,
    const void* __restrict__ dtb, float* __restrict__ dtf, const int* __restrict__ flag)
{
  int f = *flag;
  int idx = blockIdx.x * 256 + threadIdx.x;  // row*1024 + d
  int d = idx & (DI - 1);
  int row = idx >> 10;
  float raw = load_any(dtb, d, f);
#pragma unroll
  for (int k = 0; k < 32; k++)
    raw += ssm[(size_t)row * 64 + k] * load_any(dtw, (long)d * 32 + k, f);
  dtf[idx] = softplusf(raw);
}

// ---------------- scan pass 1: per-chunk transfer product P and local state S
__global__ __launch_bounds__(256) void scan_pass1(
    const float* __restrict__ dtf, const short* __restrict__ xh, const short* __restrict__ xl,
    const float* __restrict__ ssm, const void* __restrict__ alog,
    float* __restrict__ P, float* __restrict__ S, const int* __restrict__ flag,
    int nchunk, int clen)
{
  __shared__ float sB[64][NSTATE];
  int f = *flag;
  int tid = threadIdx.x;
  int c = blockIdx.x % nchunk;
  int r = blockIdx.x / nchunk;
  int dblk = r & 3, b = r >> 2;
  int d = dblk * 256 + tid;
  int t0 = c * clen;
  for (int i = tid; i < clen * NSTATE; i += 256) {
    int rr = i >> 4, cc = i & 15;
    sB[rr][cc] = ssm[(size_t)(b * TLEN + t0 + rr) * 64 + 32 + cc];
  }
  float A2[NSTATE], st[NSTATE], Pp[NSTATE];
#pragma unroll
  for (int n = 0; n < NSTATE; n++) {
    A2[n] = -expf(load_any(alog, d * NSTATE + n, f)) * LOG2E;
    st[n] = 0.f; Pp[n] = 1.f;
  }
  __syncthreads();
  for (int tt = 0; tt < clen; tt++) {
    size_t xi = (size_t)(b * TLEN + t0 + tt) * DI + d;
    float dtv = dtf[xi];
    float xv = b2f(*(const bf16t*)&xh[xi]) + b2f(*(const bf16t*)&xl[xi]);
    float dx = dtv * xv;
#pragma unroll
    for (int n = 0; n < NSTATE; n++) {
      float e = exp2f(dtv * A2[n]);
      st[n] = e * st[n] + dx * sB[tt][n];
      Pp[n] *= e;
    }
  }
  size_t base = ((size_t)(b * nchunk + c) * NSTATE) * DI + d;
#pragma unroll
  for (int n = 0; n < NSTATE; n++) {
    P[base + (size_t)n * DI] = Pp[n];
    S[base + (size_t)n * DI] = st[n];
  }
}

// ---------------- scan pass 2: combine chunk boundaries; Sin written in-place into P
__global__ __launch_bounds__(256) void scan_pass2(
    float* __restrict__ P, const float* __restrict__ S, int nchunk)
{
  int idx = blockIdx.x * 256 + threadIdx.x;  // 0..32767 = (b, n, d)
  int d = idx & (DI - 1);
  int n = (idx >> 10) & (NSTATE - 1);
  int b = idx >> 14;
  float s = 0.f;
#pragma clang loop unroll_count(4)
  for (int c = 0; c < nchunk; c++) {
    size_t o = ((size_t)(b * nchunk + c) * NSTATE + n) * DI + d;
    float p = P[o], sv = S[o];
    P[o] = s;                 // Sin for chunk c
    s = p * s + sv;
  }
}

// ---------------- scan pass 3: full scan + D-skip + gating -> y hi/lo pair
__global__ __launch_bounds__(256) void scan_pass3(
    const float* __restrict__ dtf, const short* __restrict__ xh, const short* __restrict__ xl,
    const float* __restrict__ ssm, const void* __restrict__ alog,
    const float* __restrict__ Sin, const float* __restrict__ proj,
    const void* __restrict__ Dvec, short* __restrict__ yh, short* __restrict__ yl,
    const int* __restrict__ flag, int nchunk, int clen)
{
  __shared__ float sBC[64][2 * NSTATE];
  int f = *flag;
  int tid = threadIdx.x;
  int c = blockIdx.x % nchunk;
  int r = blockIdx.x / nchunk;
  int dblk = r & 3, b = r >> 2;
  int d = dblk * 256 + tid;
  int t0 = c * clen;
  for (int i = tid; i < clen * 2 * NSTATE; i += 256) {
    int rr = i >> 5, cc = i & 31;
    sBC[rr][cc] = ssm[(size_t)(b * TLEN + t0 + rr) * 64 + 32 + cc];
  }
  float A2[NSTATE], st[NSTATE];
  size_t base = ((size_t)(b * nchunk + c) * NSTATE) * DI + d;
#pragma unroll
  for (int n = 0; n < NSTATE; n++) {
    A2[n] = -expf(load_any(alog, d * NSTATE + n, f)) * LOG2E;
    st[n] = Sin[base + (size_t)n * DI];
  }
  float Dd = load_any(Dvec, d, f);
  __syncthreads();
  for (int tt = 0; tt < clen; tt++) {
    int row = b * TLEN + t0 + tt;
    size_t xi = (size_t)row * DI + d;
    float dtv = dtf[xi];
    float xv = b2f(*(const bf16t*)&xh[xi]) + b2f(*(const bf16t*)&xl[xi]);
    float dx = dtv * xv;
    float yv = 0.f;
#pragma unroll
    for (int n = 0; n < NSTATE; n++) {
      float e = exp2f(dtv * A2[n]);
      st[n] = e * st[n] + dx * sBC[tt][n];
      yv += st[n] * sBC[tt][NSTATE + n];
    }
    float g = proj[(size_t)row * 2048 + 1024 + d];
    float sig = 1.f / (1.f + expf(-g));
    float out = (yv + xv * Dd) * (g * sig);
    bf16t h = f2b(out);
    yh[xi] = *(short*)&h;
    bf16t l = f2b(out - b2f(h));
    yl[xi] = *(short*)&l;
  }
}

extern "C" void kernel_launch(void* const* d_in, const int* in_sizes, int n_in,
                              void* d_out, int out_size, void* d_ws, size_t ws_size,
                              hipStream_t stream) {
  const void* x    = d_in[0];   // [2,2048,512]
  const void* w1   = d_in[1];   // [2048,512]
  const void* cw   = d_in[2];   // [1024,1,4]
  const void* cb   = d_in[3];   // [1024]
  const void* xw   = d_in[4];   // [64,1024]
  const void* dtw  = d_in[5];   // [1024,32]
  const void* dtb  = d_in[6];   // [1024]
  const void* alog = d_in[7];   // [1024,16]
  const void* Dv   = d_in[8];   // [1024]
  const void* w3   = d_in[9];   // [512,1024]

  char* ws = (char*)d_ws;
  int*   flag = (int*)ws;              ws += 256;
  float* proj = (float*)ws;            ws += (size_t)4096 * 2048 * 4;   // 33.55 MB
  short* xt_h = (short*)ws;            ws += (size_t)4096 * 1024 * 2;   // 8.39 MB
  short* xt_l = (short*)ws;            ws += (size_t)4096 * 1024 * 2;
  float* ssm  = (float*)ws;            ws += (size_t)4096 * 64 * 4;     // 1.05 MB
  short* y_h  = (short*)ws;            ws += (size_t)4096 * 1024 * 2;   // 8.39 MB
  short* y_l  = (short*)ws;            ws += (size_t)4096 * 1024 * 2;
  float* dtf  = (float*)ws;            ws += (size_t)4096 * 1024 * 4;   // 16.78 MB
  short* smH  = (short*)ws;            ws += (size_t)589824 * 2;        // 1.18 MB
  short* smL  = (short*)ws;            ws += (size_t)589824 * 2;
  char*  R    = ws;                                                      // PS region / cast staging

  size_t fixed = (size_t)(ws - (char*)d_ws);
  // pick largest nchunk whose P+S (2 * 2*nchunk*16*1024*4 bytes) fits alongside fixed
  int nchunk = 128;
  while (nchunk > 32) {
    size_t region = (size_t)262144 * nchunk;
    if (region < 12582912) region = 12582912;   // cast staging floor
    if (fixed + region <= ws_size) break;
    nchunk >>= 1;
  }
  int clen = TLEN / nchunk;

  short* bigH = (short*)R;                       // x @0, w1 @2097152 (hi/lo)
  short* bigL = (short*)(R + 6291456);
  float* P    = (float*)R;                       // after in_proj, region becomes P|S
  float* S    = (float*)(R + (size_t)131072 * nchunk);

  detect_dtype<<<1, 256, 0, stream>>>((const unsigned int*)x, flag);
  cast_hilo<<<dim3(14592), 256, 0, stream>>>(x, w1, xw, w3, bigH, bigL, smH, smL, flag);
  // in_proj: [4096,512] x [2048,512]^T -> proj fp32 [4096,2048]
  gemm_split<128><<<dim3(32, 16), 256, 0, stream>>>(
      bigH, bigL, bigH + 2097152, bigL + 2097152, proj, 512, 512, 512, 2048);
  // depthwise conv + silu -> xt hi/lo
  conv_silu<<<dim3(16384), 256, 0, stream>>>(proj, cw, cb, xt_h, xt_l, flag);
  // x_proj: [4096,1024] x [64,1024]^T -> ssm fp32 [4096,64]
  gemm_split<64><<<dim3(64, 1), 256, 0, stream>>>(
      xt_h, xt_l, smH, smL, ssm, 1024, 1024, 1024, 64);
  // dt precompute (softplus fused)
  dt_kernel<<<dim3(16384), 256, 0, stream>>>(ssm, dtw, dtb, dtf, flag);
  // chunked linear-recurrence scan -> y hi/lo
  scan_pass1<<<dim3(8 * nchunk), 256, 0, stream>>>(dtf, xt_h, xt_l, ssm, alog, P, S,
                                                   flag, nchunk, clen);
  scan_pass2<<<dim3(128), 256, 0, stream>>>(P, S, nchunk);
  scan_pass3<<<dim3(8 * nchunk), 256, 0, stream>>>(dtf, xt_h, xt_l, ssm, alog, P, proj,
                                                   Dv, y_h, y_l, flag, nchunk, clen);
  // out_proj: [4096,1024] x [512,1024]^T -> d_out fp32 [4096,512]
  gemm_split<128><<<dim3(32, 4), 256, 0, stream>>>(
      y_h, y_l, smH + 65536, smL + 65536, (float*)d_out, 1024, 1024, 1024, 512);
}

// Round 9
// 308.348 us; speedup vs baseline: 1.9263x; 1.9263x over previous
//
#include <hip/hip_runtime.h>
#include <hip/hip_bf16.h>
#include <math.h>

typedef __hip_bfloat16 bf16t;
typedef __attribute__((ext_vector_type(8))) short short8;
typedef __attribute__((ext_vector_type(4))) float f32x4;

#define DI 1024
#define NSTATE 16
#define TLEN 2048
#define LOG2E 1.4426950408889634f

__device__ __forceinline__ float b2f(bf16t v) { return __bfloat162float(v); }
__device__ __forceinline__ bf16t f2b(float v) { return __float2bfloat16(v); }
__device__ __forceinline__ float softplusf(float v) { return (v > 20.f) ? v : log1pf(expf(v)); }

// runtime-dtype load for RAW INPUTS: f=1 -> fp32, f=0 -> bf16
__device__ __forceinline__ float load_any(const void* s, long i, int f) {
  return f ? ((const float*)s)[i] : b2f(((const bf16t*)s)[i]);
}

__device__ __forceinline__ void async16(const void* g, void* l) {
  __builtin_amdgcn_global_load_lds(
      (const __attribute__((address_space(1))) unsigned int*)g,
      (__attribute__((address_space(3))) unsigned int*)l, 16, 0, 0);
}

// ---------------- dtype detect: flag=1 if inputs are fp32, 0 if bf16
__global__ __launch_bounds__(256) void detect_dtype(const unsigned int* __restrict__ x,
                                                    int* __restrict__ flag) {
  __shared__ int cnt;
  if (threadIdx.x == 0) cnt = 0;
  __syncthreads();
  unsigned int w = x[threadIdx.x];
  int e = (w >> 7) & 0xFF;
  if (e >= 110 && e <= 135) atomicAdd(&cnt, 1);
  __syncthreads();
  if (threadIdx.x == 0) *flag = (cnt < 128) ? 1 : 0;
}

// ---------------- hi/lo split cast of the 5 GEMM matrices
// big (aliased over P/S): x[0,2097152) w1[2097152,3145728)
// small (persistent): xw[0,65536) w3[65536,589824) dtw[589824,622592)
__global__ __launch_bounds__(256) void cast_hilo(
    const void* __restrict__ x, const void* __restrict__ w1,
    const void* __restrict__ xw, const void* __restrict__ w3, const void* __restrict__ dtw,
    short* __restrict__ bigH, short* __restrict__ bigL,
    short* __restrict__ smallH, short* __restrict__ smallL,
    const int* __restrict__ flag) {
  int i = blockIdx.x * 256 + threadIdx.x;   // 0 .. 3768320
  int f = *flag;
  float v; short *dh, *dl; int o;
  if (i < 3145728) {
    v = (i < 2097152) ? load_any(x, i, f) : load_any(w1, i - 2097152, f);
    dh = bigH; dl = bigL; o = i;
  } else {
    int j = i - 3145728;
    if (j < 65536)       v = load_any(xw, j, f);
    else if (j < 589824) v = load_any(w3, j - 65536, f);
    else                 v = load_any(dtw, j - 589824, f);
    dh = smallH; dl = smallL; o = j;
  }
  bf16t h = f2b(v);
  dh[o] = *(short*)&h;
  bf16t l = f2b(v - b2f(h));
  dl[o] = *(short*)&l;
}

// ---------------- cast ssm dt-slice [4096, 0:32] -> hi/lo pair with row stride 32
__global__ __launch_bounds__(256) void cast_ssmdt(
    const float* __restrict__ ssm, short* __restrict__ H, short* __restrict__ L) {
  int i = blockIdx.x * 256 + threadIdx.x;  // 0 .. 131072
  int row = i >> 5, k = i & 31;
  float v = ssm[(size_t)row * 64 + k];
  bf16t h = f2b(v);
  H[i] = *(short*)&h;
  bf16t l = f2b(v - b2f(h));
  L[i] = *(short*)&l;
}

// ---------------- split-bf16 MFMA GEMM: C[M,N] (fp32) = A[M,K] * B[N,K]^T
// MODE 0: plain fp32 store. MODE 1: + bias (raw input dtype) then softplus.
template <int BM, int MODE>
__global__ __launch_bounds__(256) void gemm_split(
    const short* __restrict__ Ah, const short* __restrict__ Al,
    const short* __restrict__ Bh, const short* __restrict__ Bl,
    float* __restrict__ C, int K, int lda, int ldb, int ldc,
    const void* __restrict__ bias, const int* __restrict__ flag)
{
  constexpr int NF = BM / 32;
  __shared__ __align__(16) short lAh[BM * 32], lAl[BM * 32], lBh[BM * 32], lBl[BM * 32];
  int tid = threadIdx.x;
  int lane = tid & 63, wave = tid >> 6;
  int bm = blockIdx.x * BM, bn = blockIdx.y * BM;
  int wm = (wave & 1) * (BM / 2), wn = (wave >> 1) * (BM / 2);
  f32x4 acc[NF][NF] = {};
  int r0 = tid >> 2, kp = (tid & 3) * 8;
  const short* pAh = Ah + (size_t)(bm + r0) * lda + kp;
  const short* pAl = Al + (size_t)(bm + r0) * lda + kp;
  const short* pBh = Bh + (size_t)(bn + r0) * ldb + kp;
  const short* pBl = Bl + (size_t)(bn + r0) * ldb + kp;
  int ldsOff = tid * 8;
  int la = (lane & 15) * 32 + (lane >> 4) * 8;
  for (int kk = 0; kk < K; kk += 32) {
#pragma unroll
    for (int s = 0; s < BM / 64; s++) {
      async16(pAh + kk + (size_t)s * 64 * lda, &lAh[ldsOff + s * 64 * 32]);
      async16(pAl + kk + (size_t)s * 64 * lda, &lAl[ldsOff + s * 64 * 32]);
      async16(pBh + kk + (size_t)s * 64 * ldb, &lBh[ldsOff + s * 64 * 32]);
      async16(pBl + kk + (size_t)s * 64 * ldb, &lBl[ldsOff + s * 64 * 32]);
    }
    asm volatile("s_waitcnt vmcnt(0)" ::: "memory");
    __syncthreads();
    short8 ah[NF], al[NF], bh[NF], bl[NF];
#pragma unroll
    for (int i = 0; i < NF; i++) {
      ah[i] = *(const short8*)&lAh[(wm + i * 16) * 32 + la];
      al[i] = *(const short8*)&lAl[(wm + i * 16) * 32 + la];
      bh[i] = *(const short8*)&lBh[(wn + i * 16) * 32 + la];
      bl[i] = *(const short8*)&lBl[(wn + i * 16) * 32 + la];
    }
#pragma unroll
    for (int i = 0; i < NF; i++)
#pragma unroll
      for (int j = 0; j < NF; j++) {
        acc[i][j] = __builtin_amdgcn_mfma_f32_16x16x32_bf16(ah[i], bh[j], acc[i][j], 0, 0, 0);
        acc[i][j] = __builtin_amdgcn_mfma_f32_16x16x32_bf16(ah[i], bl[j], acc[i][j], 0, 0, 0);
        acc[i][j] = __builtin_amdgcn_mfma_f32_16x16x32_bf16(al[i], bh[j], acc[i][j], 0, 0, 0);
      }
    __syncthreads();
  }
  int f = (MODE == 1) ? *flag : 0;
  int rbase = (lane >> 4) * 4, ncol = lane & 15;
#pragma unroll
  for (int i = 0; i < NF; i++)
#pragma unroll
    for (int j = 0; j < NF; j++)
#pragma unroll
      for (int r = 0; r < 4; r++) {
        int m = bm + wm + i * 16 + rbase + r;
        int n = bn + wn + j * 16 + ncol;
        float v = acc[i][j][r];
        if (MODE == 1) v = softplusf(v + load_any(bias, n, f));
        C[(size_t)m * ldc + n] = v;
      }
}

// ---------------- depthwise causal conv(K=4) + SiLU -> xt as bf16 hi/lo pair
__global__ __launch_bounds__(256) void conv_silu(
    const float* __restrict__ proj, const void* __restrict__ cw,
    const void* __restrict__ cb, short* __restrict__ xh, short* __restrict__ xl,
    const int* __restrict__ flag)
{
  int f = *flag;
  int idx = blockIdx.x * 256 + threadIdx.x;
  int d = idx & (DI - 1);
  int row = idx >> 10;
  int t = row & (TLEN - 1);
  float acc = load_any(cb, d, f);
#pragma unroll
  for (int k = 0; k < 4; k++) {
    int ts = t - 3 + k;
    if (ts >= 0) acc += load_any(cw, d * 4 + k, f) * proj[(size_t)(row - 3 + k) * 2048 + d];
  }
  float s = acc / (1.f + expf(-acc));
  bf16t h = f2b(s);
  xh[idx] = *(short*)&h;
  bf16t l = f2b(s - b2f(h));
  xl[idx] = *(short*)&l;
}

// ---------------- scan pass 1: per-chunk transfer product P and local state S
__global__ __launch_bounds__(256) void scan_pass1(
    const float* __restrict__ dtf, const short* __restrict__ xh, const short* __restrict__ xl,
    const float* __restrict__ ssm, const void* __restrict__ alog,
    float* __restrict__ P, float* __restrict__ S, const int* __restrict__ flag,
    int nchunk, int clen)
{
  __shared__ float sB[64][NSTATE];
  int f = *flag;
  int tid = threadIdx.x;
  int c = blockIdx.x % nchunk;
  int r = blockIdx.x / nchunk;
  int dblk = r & 3, b = r >> 2;
  int d = dblk * 256 + tid;
  int t0 = c * clen;
  for (int i = tid; i < clen * NSTATE; i += 256) {
    int rr = i >> 4, cc = i & 15;
    sB[rr][cc] = ssm[(size_t)(b * TLEN + t0 + rr) * 64 + 32 + cc];
  }
  float A2[NSTATE], st[NSTATE], Pp[NSTATE];
#pragma unroll
  for (int n = 0; n < NSTATE; n++) {
    A2[n] = -expf(load_any(alog, d * NSTATE + n, f)) * LOG2E;
    st[n] = 0.f; Pp[n] = 1.f;
  }
  __syncthreads();
  for (int tt = 0; tt < clen; tt++) {
    size_t xi = (size_t)(b * TLEN + t0 + tt) * DI + d;
    float dtv = dtf[xi];
    float xv = b2f(*(const bf16t*)&xh[xi]) + b2f(*(const bf16t*)&xl[xi]);
    float dx = dtv * xv;
#pragma unroll
    for (int n = 0; n < NSTATE; n++) {
      float e = exp2f(dtv * A2[n]);
      st[n] = e * st[n] + dx * sB[tt][n];
      Pp[n] *= e;
    }
  }
  size_t base = ((size_t)(b * nchunk + c) * NSTATE) * DI + d;
#pragma unroll
  for (int n = 0; n < NSTATE; n++) {
    P[base + (size_t)n * DI] = Pp[n];
    S[base + (size_t)n * DI] = st[n];
  }
}

// ---------------- scan pass 2: combine chunk boundaries; Sin written in-place into P
__global__ __launch_bounds__(256) void scan_pass2(
    float* __restrict__ P, const float* __restrict__ S, int nchunk)
{
  int idx = blockIdx.x * 256 + threadIdx.x;  // 0..32767 = (b, n, d)
  int d = idx & (DI - 1);
  int n = (idx >> 10) & (NSTATE - 1);
  int b = idx >> 14;
  float s = 0.f;
#pragma clang loop unroll_count(4)
  for (int c = 0; c < nchunk; c++) {
    size_t o = ((size_t)(b * nchunk + c) * NSTATE + n) * DI + d;
    float p = P[o], sv = S[o];
    P[o] = s;                 // Sin for chunk c
    s = p * s + sv;
  }
}

// ---------------- scan pass 3: full scan + D-skip + gating -> y hi/lo pair
__global__ __launch_bounds__(256) void scan_pass3(
    const float* __restrict__ dtf, const short* __restrict__ xh, const short* __restrict__ xl,
    const float* __restrict__ ssm, const void* __restrict__ alog,
    const float* __restrict__ Sin, const float* __restrict__ proj,
    const void* __restrict__ Dvec, short* __restrict__ yh, short* __restrict__ yl,
    const int* __restrict__ flag, int nchunk, int clen)
{
  __shared__ float sBC[64][2 * NSTATE];
  int f = *flag;
  int tid = threadIdx.x;
  int c = blockIdx.x % nchunk;
  int r = blockIdx.x / nchunk;
  int dblk = r & 3, b = r >> 2;
  int d = dblk * 256 + tid;
  int t0 = c * clen;
  for (int i = tid; i < clen * 2 * NSTATE; i += 256) {
    int rr = i >> 5, cc = i & 31;
    sBC[rr][cc] = ssm[(size_t)(b * TLEN + t0 + rr) * 64 + 32 + cc];
  }
  float A2[NSTATE], st[NSTATE];
  size_t base = ((size_t)(b * nchunk + c) * NSTATE) * DI + d;
#pragma unroll
  for (int n = 0; n < NSTATE; n++) {
    A2[n] = -expf(load_any(alog, d * NSTATE + n, f)) * LOG2E;
    st[n] = Sin[base + (size_t)n * DI];
  }
  float Dd = load_any(Dvec, d, f);
  __syncthreads();
  for (int tt = 0; tt < clen; tt++) {
    int row = b * TLEN + t0 + tt;
    size_t xi = (size_t)row * DI + d;
    float dtv = dtf[xi];
    float xv = b2f(*(const bf16t*)&xh[xi]) + b2f(*(const bf16t*)&xl[xi]);
    float dx = dtv * xv;
    float yv = 0.f;
#pragma unroll
    for (int n = 0; n < NSTATE; n++) {
      float e = exp2f(dtv * A2[n]);
      st[n] = e * st[n] + dx * sBC[tt][n];
      yv += st[n] * sBC[tt][NSTATE + n];
    }
    float g = proj[(size_t)row * 2048 + 1024 + d];
    float sig = 1.f / (1.f + expf(-g));
    float out = (yv + xv * Dd) * (g * sig);
    bf16t h = f2b(out);
    yh[xi] = *(short*)&h;
    bf16t l = f2b(out - b2f(h));
    yl[xi] = *(short*)&l;
  }
}

extern "C" void kernel_launch(void* const* d_in, const int* in_sizes, int n_in,
                              void* d_out, int out_size, void* d_ws, size_t ws_size,
                              hipStream_t stream) {
  const void* x    = d_in[0];   // [2,2048,512]
  const void* w1   = d_in[1];   // [2048,512]
  const void* cw   = d_in[2];   // [1024,1,4]
  const void* cb   = d_in[3];   // [1024]
  const void* xw   = d_in[4];   // [64,1024]
  const void* dtw  = d_in[5];   // [1024,32]
  const void* dtb  = d_in[6];   // [1024]
  const void* alog = d_in[7];   // [1024,16]
  const void* Dv   = d_in[8];   // [1024]
  const void* w3   = d_in[9];   // [512,1024]

  char* ws = (char*)d_ws;
  int*   flag = (int*)ws;              ws += 256;
  float* proj = (float*)ws;            ws += (size_t)4096 * 2048 * 4;   // 33.55 MB
  short* xt_h = (short*)ws;            ws += (size_t)4096 * 1024 * 2;   // 8.39 MB
  short* xt_l = (short*)ws;            ws += (size_t)4096 * 1024 * 2;
  float* ssm  = (float*)ws;            ws += (size_t)4096 * 64 * 4;     // 1.05 MB
  short* y_h  = (short*)ws;            ws += (size_t)4096 * 1024 * 2;   // 8.39 MB
  short* y_l  = (short*)ws;            ws += (size_t)4096 * 1024 * 2;
  float* dtf  = (float*)ws;            ws += (size_t)4096 * 1024 * 4;   // 16.78 MB
  short* smH  = (short*)ws;            ws += (size_t)622592 * 2;        // 1.25 MB
  short* smL  = (short*)ws;            ws += (size_t)622592 * 2;
  short* sdH  = (short*)ws;            ws += (size_t)131072 * 2;        // 0.26 MB
  short* sdL  = (short*)ws;            ws += (size_t)131072 * 2;
  char*  R    = ws;                                                      // PS region / cast staging

  size_t fixed = (size_t)(ws - (char*)d_ws);
  int nchunk = 128;
  while (nchunk > 32) {
    size_t region = (size_t)262144 * nchunk;
    if (region < 12582912) region = 12582912;   // cast staging floor
    if (fixed + region <= ws_size) break;
    nchunk >>= 1;
  }
  int clen = TLEN / nchunk;

  short* bigH = (short*)R;                       // x @0, w1 @2097152 (hi/lo)
  short* bigL = (short*)(R + 6291456);
  float* P    = (float*)R;                       // after in_proj, region becomes P|S
  float* S    = (float*)(R + (size_t)131072 * nchunk);

  detect_dtype<<<1, 256, 0, stream>>>((const unsigned int*)x, flag);
  cast_hilo<<<dim3(14720), 256, 0, stream>>>(x, w1, xw, w3, dtw, bigH, bigL, smH, smL, flag);
  // in_proj: [4096,512] x [2048,512]^T -> proj fp32 [4096,2048]
  gemm_split<128, 0><<<dim3(32, 16), 256, 0, stream>>>(
      bigH, bigL, bigH + 2097152, bigL + 2097152, proj, 512, 512, 512, 2048, nullptr, flag);
  // depthwise conv + silu -> xt hi/lo
  conv_silu<<<dim3(16384), 256, 0, stream>>>(proj, cw, cb, xt_h, xt_l, flag);
  // x_proj: [4096,1024] x [64,1024]^T -> ssm fp32 [4096,64]
  gemm_split<64, 0><<<dim3(64, 1), 256, 0, stream>>>(
      xt_h, xt_l, smH, smL, ssm, 1024, 1024, 1024, 64, nullptr, flag);
  // dt: cast ssm[:,0:32] hi/lo, then MFMA GEMM [4096,32]x[1024,32]^T + bias + softplus
  cast_ssmdt<<<dim3(512), 256, 0, stream>>>(ssm, sdH, sdL);
  gemm_split<64, 1><<<dim3(64, 16), 256, 0, stream>>>(
      sdH, sdL, smH + 589824, smL + 589824, dtf, 32, 32, 32, 1024, dtb, flag);
  // chunked linear-recurrence scan -> y hi/lo
  scan_pass1<<<dim3(8 * nchunk), 256, 0, stream>>>(dtf, xt_h, xt_l, ssm, alog, P, S,
                                                   flag, nchunk, clen);
  scan_pass2<<<dim3(128), 256, 0, stream>>>(P, S, nchunk);
  scan_pass3<<<dim3(8 * nchunk), 256, 0, stream>>>(dtf, xt_h, xt_l, ssm, alog, P, proj,
                                                   Dv, y_h, y_l, flag, nchunk, clen);
  // out_proj: [4096,1024] x [512,1024]^T -> d_out fp32 [4096,512]
  gemm_split<128, 0><<<dim3(32, 4), 256, 0, stream>>>(
      y_h, y_l, smH + 65536, smL + 65536, (float*)d_out, 1024, 1024, 1024, 512, nullptr, flag);
}

// Round 10
// 285.835 us; speedup vs baseline: 2.0780x; 1.0788x over previous
//
#include <hip/hip_runtime.h>
#include <hip/hip_bf16.h>
#include <math.h>

typedef __hip_bfloat16 bf16t;
typedef __attribute__((ext_vector_type(8))) short short8;
typedef __attribute__((ext_vector_type(4))) float f32x4;

#define DI 1024
#define NSTATE 16
#define TLEN 2048
#define LOG2E 1.4426950408889634f

__device__ __forceinline__ float b2f(bf16t v) { return __bfloat162float(v); }
__device__ __forceinline__ bf16t f2b(float v) { return __float2bfloat16(v); }
__device__ __forceinline__ float softplusf(float v) { return (v > 20.f) ? v : log1pf(expf(v)); }

// runtime-dtype load for RAW INPUTS: f=1 -> fp32, f=0 -> bf16
__device__ __forceinline__ float load_any(const void* s, long i, int f) {
  return f ? ((const float*)s)[i] : b2f(((const bf16t*)s)[i]);
}

__device__ __forceinline__ void async16(const void* g, void* l) {
  __builtin_amdgcn_global_load_lds(
      (const __attribute__((address_space(1))) unsigned int*)g,
      (__attribute__((address_space(3))) unsigned int*)l, 16, 0, 0);
}

template <int N> __device__ __forceinline__ void waitcnt_vm() {
  if constexpr (N == 0)      asm volatile("s_waitcnt vmcnt(0)" ::: "memory");
  else if constexpr (N == 4) asm volatile("s_waitcnt vmcnt(4)" ::: "memory");
  else if constexpr (N == 8) asm volatile("s_waitcnt vmcnt(8)" ::: "memory");
}
__device__ __forceinline__ void raw_barrier() { asm volatile("s_barrier" ::: "memory"); }

// ---------------- dtype detect: flag=1 if inputs are fp32, 0 if bf16
__global__ __launch_bounds__(256) void detect_dtype(const unsigned int* __restrict__ x,
                                                    int* __restrict__ flag) {
  __shared__ int cnt;
  if (threadIdx.x == 0) cnt = 0;
  __syncthreads();
  unsigned int w = x[threadIdx.x];
  int e = (w >> 7) & 0xFF;
  if (e >= 110 && e <= 135) atomicAdd(&cnt, 1);
  __syncthreads();
  if (threadIdx.x == 0) *flag = (cnt < 128) ? 1 : 0;
}

// ---------------- hi/lo split cast of the 5 GEMM matrices
// big (aliased over P/S): x[0,2097152) w1[2097152,3145728)
// small (persistent): xw[0,65536) w3[65536,589824) dtw[589824,622592)
__global__ __launch_bounds__(256) void cast_hilo(
    const void* __restrict__ x, const void* __restrict__ w1,
    const void* __restrict__ xw, const void* __restrict__ w3, const void* __restrict__ dtw,
    short* __restrict__ bigH, short* __restrict__ bigL,
    short* __restrict__ smallH, short* __restrict__ smallL,
    const int* __restrict__ flag) {
  int i = blockIdx.x * 256 + threadIdx.x;   // 0 .. 3768320
  int f = *flag;
  float v; short *dh, *dl; int o;
  if (i < 3145728) {
    v = (i < 2097152) ? load_any(x, i, f) : load_any(w1, i - 2097152, f);
    dh = bigH; dl = bigL; o = i;
  } else {
    int j = i - 3145728;
    if (j < 65536)       v = load_any(xw, j, f);
    else if (j < 589824) v = load_any(w3, j - 65536, f);
    else                 v = load_any(dtw, j - 589824, f);
    dh = smallH; dl = smallL; o = j;
  }
  bf16t h = f2b(v);
  dh[o] = *(short*)&h;
  bf16t l = f2b(v - b2f(h));
  dl[o] = *(short*)&l;
}

// ---------------- split-bf16 MFMA GEMM, double-buffered K-loop
// C[M,N] (fp32) = A[M,K] * B[N,K]^T via Ah*Bh + Ah*Bl + Al*Bh
// MODE 0: plain. MODE 1: +bias softplus. MODE 2: fp32 + hi/lo bf16 copy of cols<32.
template <int BM, int BN, int MODE>
__global__ __launch_bounds__(256) void gemm_split(
    const short* __restrict__ Ah, const short* __restrict__ Al,
    const short* __restrict__ Bh, const short* __restrict__ Bl,
    float* __restrict__ C, int K, int lda, int ldb, int ldc,
    const void* __restrict__ bias, const int* __restrict__ flag,
    short* __restrict__ outH, short* __restrict__ outL)
{
  constexpr int NFM = BM / 32, NFN = BN / 32;
  constexpr int SA = BM / 64, SB = BN / 64;
  constexpr int NL = 2 * (SA + SB);     // async16 per stage per thread
  __shared__ __align__(16) short lAh[2][BM * 32], lAl[2][BM * 32];
  __shared__ __align__(16) short lBh[2][BN * 32], lBl[2][BN * 32];
  int tid = threadIdx.x;
  int lane = tid & 63, wave = tid >> 6;
  int bm = blockIdx.x * BM, bn = blockIdx.y * BN;
  int wm = (wave & 1) * (BM / 2), wn = (wave >> 1) * (BN / 2);
  f32x4 acc[NFM][NFN] = {};
  int r0 = tid >> 2, kp = (tid & 3) * 8;
  const short* pAh = Ah + (size_t)(bm + r0) * lda + kp;
  const short* pAl = Al + (size_t)(bm + r0) * lda + kp;
  const short* pBh = Bh + (size_t)(bn + r0) * ldb + kp;
  const short* pBl = Bl + (size_t)(bn + r0) * ldb + kp;
  int ldsOff = tid * 8;   // tid*16 bytes, wave-contiguous (lane*16 DMA scatter)
  int la = (lane & 15) * 32 + (lane >> 4) * 8;
  int nIter = K / 32;

  auto stage = [&](int kk, int b) {
    int off = kk * 32;
#pragma unroll
    for (int s = 0; s < SA; s++) {
      async16(pAh + off + (size_t)s * 64 * lda, &lAh[b][ldsOff + s * 64 * 32]);
      async16(pAl + off + (size_t)s * 64 * lda, &lAl[b][ldsOff + s * 64 * 32]);
    }
#pragma unroll
    for (int s = 0; s < SB; s++) {
      async16(pBh + off + (size_t)s * 64 * ldb, &lBh[b][ldsOff + s * 64 * 32]);
      async16(pBl + off + (size_t)s * 64 * ldb, &lBl[b][ldsOff + s * 64 * 32]);
    }
  };

  stage(0, 0);
  for (int kk = 0; kk < nIter; kk++) {
    int cur = kk & 1;
    bool more = (kk + 1 < nIter);
    if (more) stage(kk + 1, cur ^ 1);   // keep NL loads in flight across the barrier
    if (more) waitcnt_vm<NL>(); else waitcnt_vm<0>();
    raw_barrier();
    short8 ah[NFM], al[NFM], bh[NFN], bl[NFN];
#pragma unroll
    for (int i = 0; i < NFM; i++) {
      ah[i] = *(const short8*)&lAh[cur][(wm + i * 16) * 32 + la];
      al[i] = *(const short8*)&lAl[cur][(wm + i * 16) * 32 + la];
    }
#pragma unroll
    for (int j = 0; j < NFN; j++) {
      bh[j] = *(const short8*)&lBh[cur][(wn + j * 16) * 32 + la];
      bl[j] = *(const short8*)&lBl[cur][(wn + j * 16) * 32 + la];
    }
#pragma unroll
    for (int i = 0; i < NFM; i++)
#pragma unroll
      for (int j = 0; j < NFN; j++) {
        acc[i][j] = __builtin_amdgcn_mfma_f32_16x16x32_bf16(ah[i], bh[j], acc[i][j], 0, 0, 0);
        acc[i][j] = __builtin_amdgcn_mfma_f32_16x16x32_bf16(ah[i], bl[j], acc[i][j], 0, 0, 0);
        acc[i][j] = __builtin_amdgcn_mfma_f32_16x16x32_bf16(al[i], bh[j], acc[i][j], 0, 0, 0);
      }
    raw_barrier();   // protect buf `cur` before it is re-staged next iteration
  }
  int f = (MODE == 1) ? *flag : 0;
  int rbase = (lane >> 4) * 4, ncol = lane & 15;
#pragma unroll
  for (int i = 0; i < NFM; i++)
#pragma unroll
    for (int j = 0; j < NFN; j++)
#pragma unroll
      for (int r = 0; r < 4; r++) {
        int m = bm + wm + i * 16 + rbase + r;
        int n = bn + wn + j * 16 + ncol;
        float v = acc[i][j][r];
        if (MODE == 1) v = softplusf(v + load_any(bias, n, f));
        C[(size_t)m * ldc + n] = v;
        if (MODE == 2 && n < 32) {
          bf16t h = f2b(v);
          outH[(size_t)m * 32 + n] = *(short*)&h;
          bf16t l = f2b(v - b2f(h));
          outL[(size_t)m * 32 + n] = *(short*)&l;
        }
      }
}

// ---------------- depthwise causal conv(K=4) + SiLU -> xt as bf16 hi/lo pair
__global__ __launch_bounds__(256) void conv_silu(
    const float* __restrict__ proj, const void* __restrict__ cw,
    const void* __restrict__ cb, short* __restrict__ xh, short* __restrict__ xl,
    const int* __restrict__ flag)
{
  int f = *flag;
  int idx = blockIdx.x * 256 + threadIdx.x;
  int d = idx & (DI - 1);
  int row = idx >> 10;
  int t = row & (TLEN - 1);
  float acc = load_any(cb, d, f);
#pragma unroll
  for (int k = 0; k < 4; k++) {
    int ts = t - 3 + k;
    if (ts >= 0) acc += load_any(cw, d * 4 + k, f) * proj[(size_t)(row - 3 + k) * 2048 + d];
  }
  float s = acc / (1.f + expf(-acc));
  bf16t h = f2b(s);
  xh[idx] = *(short*)&h;
  bf16t l = f2b(s - b2f(h));
  xl[idx] = *(short*)&l;
}

// ---------------- scan pass 1: per-chunk transfer product P and local state S
__global__ __launch_bounds__(256) void scan_pass1(
    const float* __restrict__ dtf, const short* __restrict__ xh, const short* __restrict__ xl,
    const float* __restrict__ ssm, const void* __restrict__ alog,
    float* __restrict__ P, float* __restrict__ S, const int* __restrict__ flag,
    int nchunk, int clen)
{
  __shared__ float sB[64][NSTATE];
  int f = *flag;
  int tid = threadIdx.x;
  int c = blockIdx.x % nchunk;
  int r = blockIdx.x / nchunk;
  int dblk = r & 3, b = r >> 2;
  int d = dblk * 256 + tid;
  int t0 = c * clen;
  for (int i = tid; i < clen * NSTATE; i += 256) {
    int rr = i >> 4, cc = i & 15;
    sB[rr][cc] = ssm[(size_t)(b * TLEN + t0 + rr) * 64 + 32 + cc];
  }
  float A2[NSTATE], st[NSTATE], Pp[NSTATE];
#pragma unroll
  for (int n = 0; n < NSTATE; n++) {
    A2[n] = -expf(load_any(alog, d * NSTATE + n, f)) * LOG2E;
    st[n] = 0.f; Pp[n] = 1.f;
  }
  __syncthreads();
  for (int tt = 0; tt < clen; tt++) {
    size_t xi = (size_t)(b * TLEN + t0 + tt) * DI + d;
    float dtv = dtf[xi];
    float xv = b2f(*(const bf16t*)&xh[xi]) + b2f(*(const bf16t*)&xl[xi]);
    float dx = dtv * xv;
#pragma unroll
    for (int n = 0; n < NSTATE; n++) {
      float e = exp2f(dtv * A2[n]);
      st[n] = e * st[n] + dx * sB[tt][n];
      Pp[n] *= e;
    }
  }
  size_t base = ((size_t)(b * nchunk + c) * NSTATE) * DI + d;
#pragma unroll
  for (int n = 0; n < NSTATE; n++) {
    P[base + (size_t)n * DI] = Pp[n];
    S[base + (size_t)n * DI] = st[n];
  }
}

// ---------------- scan pass 2: combine chunk boundaries; Sin written in-place into P
__global__ __launch_bounds__(256) void scan_pass2(
    float* __restrict__ P, const float* __restrict__ S, int nchunk)
{
  int idx = blockIdx.x * 256 + threadIdx.x;  // 0..32767 = (b, n, d)
  int d = idx & (DI - 1);
  int n = (idx >> 10) & (NSTATE - 1);
  int b = idx >> 14;
  float s = 0.f;
#pragma clang loop unroll_count(4)
  for (int c = 0; c < nchunk; c++) {
    size_t o = ((size_t)(b * nchunk + c) * NSTATE + n) * DI + d;
    float p = P[o], sv = S[o];
    P[o] = s;                 // Sin for chunk c
    s = p * s + sv;
  }
}

// ---------------- scan pass 3: full scan + D-skip + gating -> y hi/lo pair
__global__ __launch_bounds__(256) void scan_pass3(
    const float* __restrict__ dtf, const short* __restrict__ xh, const short* __restrict__ xl,
    const float* __restrict__ ssm, const void* __restrict__ alog,
    const float* __restrict__ Sin, const float* __restrict__ proj,
    const void* __restrict__ Dvec, short* __restrict__ yh, short* __restrict__ yl,
    const int* __restrict__ flag, int nchunk, int clen)
{
  __shared__ float sBC[64][2 * NSTATE];
  int f = *flag;
  int tid = threadIdx.x;
  int c = blockIdx.x % nchunk;
  int r = blockIdx.x / nchunk;
  int dblk = r & 3, b = r >> 2;
  int d = dblk * 256 + tid;
  int t0 = c * clen;
  for (int i = tid; i < clen * 2 * NSTATE; i += 256) {
    int rr = i >> 5, cc = i & 31;
    sBC[rr][cc] = ssm[(size_t)(b * TLEN + t0 + rr) * 64 + 32 + cc];
  }
  float A2[NSTATE], st[NSTATE];
  size_t base = ((size_t)(b * nchunk + c) * NSTATE) * DI + d;
#pragma unroll
  for (int n = 0; n < NSTATE; n++) {
    A2[n] = -expf(load_any(alog, d * NSTATE + n, f)) * LOG2E;
    st[n] = Sin[base + (size_t)n * DI];
  }
  float Dd = load_any(Dvec, d, f);
  __syncthreads();
  for (int tt = 0; tt < clen; tt++) {
    int row = b * TLEN + t0 + tt;
    size_t xi = (size_t)row * DI + d;
    float dtv = dtf[xi];
    float xv = b2f(*(const bf16t*)&xh[xi]) + b2f(*(const bf16t*)&xl[xi]);
    float dx = dtv * xv;
    float yv = 0.f;
#pragma unroll
    for (int n = 0; n < NSTATE; n++) {
      float e = exp2f(dtv * A2[n]);
      st[n] = e * st[n] + dx * sBC[tt][n];
      yv += st[n] * sBC[tt][NSTATE + n];
    }
    float g = proj[(size_t)row * 2048 + 1024 + d];
    float sig = 1.f / (1.f + expf(-g));
    float out = (yv + xv * Dd) * (g * sig);
    bf16t h = f2b(out);
    yh[xi] = *(short*)&h;
    bf16t l = f2b(out - b2f(h));
    yl[xi] = *(short*)&l;
  }
}

extern "C" void kernel_launch(void* const* d_in, const int* in_sizes, int n_in,
                              void* d_out, int out_size, void* d_ws, size_t ws_size,
                              hipStream_t stream) {
  const void* x    = d_in[0];   // [2,2048,512]
  const void* w1   = d_in[1];   // [2048,512]
  const void* cw   = d_in[2];   // [1024,1,4]
  const void* cb   = d_in[3];   // [1024]
  const void* xw   = d_in[4];   // [64,1024]
  const void* dtw  = d_in[5];   // [1024,32]
  const void* dtb  = d_in[6];   // [1024]
  const void* alog = d_in[7];   // [1024,16]
  const void* Dv   = d_in[8];   // [1024]
  const void* w3   = d_in[9];   // [512,1024]

  char* ws = (char*)d_ws;
  int*   flag = (int*)ws;              ws += 256;
  float* proj = (float*)ws;            ws += (size_t)4096 * 2048 * 4;   // 33.55 MB
  short* xt_h = (short*)ws;            ws += (size_t)4096 * 1024 * 2;   // 8.39 MB
  short* xt_l = (short*)ws;            ws += (size_t)4096 * 1024 * 2;
  float* ssm  = (float*)ws;            ws += (size_t)4096 * 64 * 4;     // 1.05 MB
  short* y_h  = (short*)ws;            ws += (size_t)4096 * 1024 * 2;   // 8.39 MB
  short* y_l  = (short*)ws;            ws += (size_t)4096 * 1024 * 2;
  float* dtf  = (float*)ws;            ws += (size_t)4096 * 1024 * 4;   // 16.78 MB
  short* smH  = (short*)ws;            ws += (size_t)622592 * 2;        // 1.25 MB
  short* smL  = (short*)ws;            ws += (size_t)622592 * 2;
  short* sdH  = (short*)ws;            ws += (size_t)131072 * 2;        // 0.26 MB
  short* sdL  = (short*)ws;            ws += (size_t)131072 * 2;
  char*  R    = ws;                                                      // PS region / cast staging

  size_t fixed = (size_t)(ws - (char*)d_ws);
  int nchunk = 128;
  while (nchunk > 32) {
    size_t region = (size_t)262144 * nchunk;
    if (region < 12582912) region = 12582912;   // cast staging floor
    if (fixed + region <= ws_size) break;
    nchunk >>= 1;
  }
  int clen = TLEN / nchunk;

  short* bigH = (short*)R;                       // x @0, w1 @2097152 (hi/lo)
  short* bigL = (short*)(R + 6291456);
  float* P    = (float*)R;                       // after in_proj, region becomes P|S
  float* S    = (float*)(R + (size_t)131072 * nchunk);

  detect_dtype<<<1, 256, 0, stream>>>((const unsigned int*)x, flag);
  cast_hilo<<<dim3(14720), 256, 0, stream>>>(x, w1, xw, w3, dtw, bigH, bigL, smH, smL, flag);
  // in_proj: [4096,512] x [2048,512]^T -> proj fp32 [4096,2048]
  gemm_split<128, 128, 0><<<dim3(32, 16), 256, 0, stream>>>(
      bigH, bigL, bigH + 2097152, bigL + 2097152, proj, 512, 512, 512, 2048,
      nullptr, flag, nullptr, nullptr);
  // depthwise conv + silu -> xt hi/lo
  conv_silu<<<dim3(16384), 256, 0, stream>>>(proj, cw, cb, xt_h, xt_l, flag);
  // x_proj: [4096,1024] x [64,1024]^T -> ssm fp32 [4096,64] + dt-slice hi/lo (fused)
  gemm_split<64, 64, 2><<<dim3(64, 1), 256, 0, stream>>>(
      xt_h, xt_l, smH, smL, ssm, 1024, 1024, 1024, 64, nullptr, flag, sdH, sdL);
  // dt: MFMA GEMM [4096,32] x [1024,32]^T + bias + softplus -> dtf
  gemm_split<64, 64, 1><<<dim3(64, 16), 256, 0, stream>>>(
      sdH, sdL, smH + 589824, smL + 589824, dtf, 32, 32, 32, 1024, dtb, flag,
      nullptr, nullptr);
  // chunked linear-recurrence scan -> y hi/lo
  scan_pass1<<<dim3(8 * nchunk), 256, 0, stream>>>(dtf, xt_h, xt_l, ssm, alog, P, S,
                                                   flag, nchunk, clen);
  scan_pass2<<<dim3(128), 256, 0, stream>>>(P, S, nchunk);
  scan_pass3<<<dim3(8 * nchunk), 256, 0, stream>>>(dtf, xt_h, xt_l, ssm, alog, P, proj,
                                                   Dv, y_h, y_l, flag, nchunk, clen);
  // out_proj: [4096,1024] x [512,1024]^T -> d_out fp32 [4096,512]
  gemm_split<64, 64, 0><<<dim3(64, 8), 256, 0, stream>>>(
      y_h, y_l, smH + 65536, smL + 65536, (float*)d_out, 1024, 1024, 1024, 512,
      nullptr, flag, nullptr, nullptr);
}

// Round 11
// 280.469 us; speedup vs baseline: 2.1178x; 1.0191x over previous
//
#include <hip/hip_runtime.h>
#include <hip/hip_bf16.h>
#include <math.h>

typedef __hip_bfloat16 bf16t;
typedef __attribute__((ext_vector_type(8))) short short8;
typedef __attribute__((ext_vector_type(4))) float f32x4;

#define DI 1024
#define NSTATE 16
#define TLEN 2048
#define LOG2E 1.4426950408889634f

__device__ __forceinline__ float b2f(bf16t v) { return __bfloat162float(v); }
__device__ __forceinline__ bf16t f2b(float v) { return __float2bfloat16(v); }
__device__ __forceinline__ float fexp2(float x) { return __builtin_amdgcn_exp2f(x); }
__device__ __forceinline__ float flog2(float x) { return __builtin_amdgcn_logf(x); }
// fast softplus: log(1+e^v)
__device__ __forceinline__ float softplus_fast(float v) {
  return (v > 20.f) ? v : flog2(1.f + fexp2(v * LOG2E)) * (1.f / LOG2E);
}

// wave-ballot dtype detect on first 64 words of x: 1 = fp32 inputs, 0 = bf16
__device__ __forceinline__ int detect_f(const unsigned int* __restrict__ x0) {
  unsigned int w = x0[threadIdx.x & 63];
  int e = (w >> 7) & 0xFF;
  unsigned long long m = __ballot(e >= 110 && e <= 135);
  return (__popcll(m) < 32) ? 1 : 0;
}

// runtime-dtype load for RAW INPUTS: f=1 -> fp32, f=0 -> bf16
__device__ __forceinline__ float load_any(const void* s, long i, int f) {
  return f ? ((const float*)s)[i] : b2f(((const bf16t*)s)[i]);
}

__device__ __forceinline__ void async16(const void* g, void* l) {
  __builtin_amdgcn_global_load_lds(
      (const __attribute__((address_space(1))) unsigned int*)g,
      (__attribute__((address_space(3))) unsigned int*)l, 16, 0, 0);
}

template <int N> __device__ __forceinline__ void waitcnt_vm() {
  if constexpr (N == 0)      asm volatile("s_waitcnt vmcnt(0)" ::: "memory");
  else if constexpr (N == 4) asm volatile("s_waitcnt vmcnt(4)" ::: "memory");
  else if constexpr (N == 8) asm volatile("s_waitcnt vmcnt(8)" ::: "memory");
}
__device__ __forceinline__ void raw_barrier() { asm volatile("s_barrier" ::: "memory"); }

// ---------------- hi/lo split cast of the 5 GEMM matrices (4 elems/thread)
// big (aliased over P/S): x[0,2097152) w1[2097152,3145728)
// small (persistent): xw[0,65536) w3[65536,589824) dtw[589824,622592)
__global__ __launch_bounds__(256) void cast_hilo(
    const void* __restrict__ x, const void* __restrict__ w1,
    const void* __restrict__ xw, const void* __restrict__ w3, const void* __restrict__ dtw,
    short* __restrict__ bigH, short* __restrict__ bigL,
    short* __restrict__ smallH, short* __restrict__ smallL)
{
  int f = detect_f((const unsigned int*)x);
  int i0 = (blockIdx.x * 256 + threadIdx.x) * 4;
#pragma unroll
  for (int q = 0; q < 4; q++) {
    int i = i0 + q;
    if (i >= 3768320) return;
    float v; short *dh, *dl; int o;
    if (i < 3145728) {
      v = (i < 2097152) ? load_any(x, i, f) : load_any(w1, i - 2097152, f);
      dh = bigH; dl = bigL; o = i;
    } else {
      int j = i - 3145728;
      if (j < 65536)       v = load_any(xw, j, f);
      else if (j < 589824) v = load_any(w3, j - 65536, f);
      else                 v = load_any(dtw, j - 589824, f);
      dh = smallH; dl = smallL; o = j;
    }
    bf16t h = f2b(v);
    dh[o] = *(short*)&h;
    bf16t l = f2b(v - b2f(h));
    dl[o] = *(short*)&l;
  }
}

// ---------------- split-bf16 MFMA GEMM, double-buffered K-loop
// C[M,N] (fp32) = A[M,K] * B[N,K]^T via Ah*Bh + Ah*Bl + Al*Bh
// MODE 0: plain. MODE 1: +bias softplus. MODE 2: fp32 + hi/lo bf16 copy of cols<32.
template <int BM, int BN, int MODE>
__global__ __launch_bounds__(256) void gemm_split(
    const short* __restrict__ Ah, const short* __restrict__ Al,
    const short* __restrict__ Bh, const short* __restrict__ Bl,
    float* __restrict__ C, int K, int lda, int ldb, int ldc,
    const void* __restrict__ bias, const unsigned int* __restrict__ x0,
    short* __restrict__ outH, short* __restrict__ outL)
{
  constexpr int NFM = BM / 32, NFN = BN / 32;
  constexpr int SA = BM / 64, SB = BN / 64;
  constexpr int NL = 2 * (SA + SB);
  __shared__ __align__(16) short lAh[2][BM * 32], lAl[2][BM * 32];
  __shared__ __align__(16) short lBh[2][BN * 32], lBl[2][BN * 32];
  int tid = threadIdx.x;
  int lane = tid & 63, wave = tid >> 6;
  int bm = blockIdx.x * BM, bn = blockIdx.y * BN;
  int wm = (wave & 1) * (BM / 2), wn = (wave >> 1) * (BN / 2);
  f32x4 acc[NFM][NFN] = {};
  int r0 = tid >> 2, kp = (tid & 3) * 8;
  const short* pAh = Ah + (size_t)(bm + r0) * lda + kp;
  const short* pAl = Al + (size_t)(bm + r0) * lda + kp;
  const short* pBh = Bh + (size_t)(bn + r0) * ldb + kp;
  const short* pBl = Bl + (size_t)(bn + r0) * ldb + kp;
  int ldsOff = tid * 8;
  int la = (lane & 15) * 32 + (lane >> 4) * 8;
  int nIter = K / 32;

  auto stage = [&](int kk, int b) {
    int off = kk * 32;
#pragma unroll
    for (int s = 0; s < SA; s++) {
      async16(pAh + off + (size_t)s * 64 * lda, &lAh[b][ldsOff + s * 64 * 32]);
      async16(pAl + off + (size_t)s * 64 * lda, &lAl[b][ldsOff + s * 64 * 32]);
    }
#pragma unroll
    for (int s = 0; s < SB; s++) {
      async16(pBh + off + (size_t)s * 64 * ldb, &lBh[b][ldsOff + s * 64 * 32]);
      async16(pBl + off + (size_t)s * 64 * ldb, &lBl[b][ldsOff + s * 64 * 32]);
    }
  };

  stage(0, 0);
  for (int kk = 0; kk < nIter; kk++) {
    int cur = kk & 1;
    bool more = (kk + 1 < nIter);
    if (more) stage(kk + 1, cur ^ 1);
    if (more) waitcnt_vm<NL>(); else waitcnt_vm<0>();
    raw_barrier();
    short8 ah[NFM], al[NFM], bh[NFN], bl[NFN];
#pragma unroll
    for (int i = 0; i < NFM; i++) {
      ah[i] = *(const short8*)&lAh[cur][(wm + i * 16) * 32 + la];
      al[i] = *(const short8*)&lAl[cur][(wm + i * 16) * 32 + la];
    }
#pragma unroll
    for (int j = 0; j < NFN; j++) {
      bh[j] = *(const short8*)&lBh[cur][(wn + j * 16) * 32 + la];
      bl[j] = *(const short8*)&lBl[cur][(wn + j * 16) * 32 + la];
    }
#pragma unroll
    for (int i = 0; i < NFM; i++)
#pragma unroll
      for (int j = 0; j < NFN; j++) {
        acc[i][j] = __builtin_amdgcn_mfma_f32_16x16x32_bf16(ah[i], bh[j], acc[i][j], 0, 0, 0);
        acc[i][j] = __builtin_amdgcn_mfma_f32_16x16x32_bf16(ah[i], bl[j], acc[i][j], 0, 0, 0);
        acc[i][j] = __builtin_amdgcn_mfma_f32_16x16x32_bf16(al[i], bh[j], acc[i][j], 0, 0, 0);
      }
    raw_barrier();
  }
  int f = (MODE == 1) ? detect_f(x0) : 0;
  int rbase = (lane >> 4) * 4, ncol = lane & 15;
#pragma unroll
  for (int i = 0; i < NFM; i++)
#pragma unroll
    for (int j = 0; j < NFN; j++)
#pragma unroll
      for (int r = 0; r < 4; r++) {
        int m = bm + wm + i * 16 + rbase + r;
        int n = bn + wn + j * 16 + ncol;
        float v = acc[i][j][r];
        if (MODE == 1) v = softplus_fast(v + load_any(bias, n, f));
        C[(size_t)m * ldc + n] = v;
        if (MODE == 2 && n < 32) {
          bf16t h = f2b(v);
          outH[(size_t)m * 32 + n] = *(short*)&h;
          bf16t l = f2b(v - b2f(h));
          outL[(size_t)m * 32 + n] = *(short*)&l;
        }
      }
}

// ---------------- depthwise causal conv(K=4)+SiLU -> xt hi/lo; also silu(gate) in-place
__global__ __launch_bounds__(256) void conv_silu(
    const float* __restrict__ projc, float* __restrict__ proj,
    const void* __restrict__ cw, const void* __restrict__ cb,
    short* __restrict__ xh, short* __restrict__ xl, const unsigned int* __restrict__ x0)
{
  int f = detect_f(x0);
  int idx = blockIdx.x * 256 + threadIdx.x;
  int d = idx & (DI - 1);
  int row = idx >> 10;
  int t = row & (TLEN - 1);
  float acc = load_any(cb, d, f);
#pragma unroll
  for (int k = 0; k < 4; k++) {
    int ts = t - 3 + k;
    if (ts >= 0) acc += load_any(cw, d * 4 + k, f) * projc[(size_t)(row - 3 + k) * 2048 + d];
  }
  float s = acc / (1.f + fexp2(-acc * LOG2E));
  bf16t h = f2b(s);
  xh[idx] = *(short*)&h;
  bf16t l = f2b(s - b2f(h));
  xl[idx] = *(short*)&l;
  // pre-apply silu to the gate half, in place
  size_t gi = (size_t)row * 2048 + 1024 + d;
  float g = projc[gi];
  proj[gi] = g / (1.f + fexp2(-g * LOG2E));
}

// ---------------- scan pass 1: per-chunk transfer product P and local state S
template <int CLEN>
__global__ __launch_bounds__(256) void scan_pass1(
    const float* __restrict__ dtf, const short* __restrict__ xh, const short* __restrict__ xl,
    const float* __restrict__ ssm, const void* __restrict__ alog,
    float* __restrict__ P, float* __restrict__ S, const unsigned int* __restrict__ x0)
{
  constexpr int NCH = TLEN / CLEN;
  __shared__ float sB[CLEN][NSTATE];
  int f = detect_f(x0);
  int tid = threadIdx.x;
  int c = blockIdx.x % NCH;
  int r = blockIdx.x / NCH;
  int dblk = r & 3, b = r >> 2;
  int d = dblk * 256 + tid;
  int t0 = c * CLEN;
  for (int i = tid; i < CLEN * NSTATE; i += 256) {
    int rr = i >> 4, cc = i & 15;
    sB[rr][cc] = ssm[(size_t)(b * TLEN + t0 + rr) * 64 + 32 + cc];
  }
  float A2[NSTATE], st[NSTATE], Pp[NSTATE];
#pragma unroll
  for (int n = 0; n < NSTATE; n++) {
    A2[n] = -fexp2(load_any(alog, d * NSTATE + n, f) * LOG2E) * LOG2E;
    st[n] = 0.f; Pp[n] = 1.f;
  }
  __syncthreads();
#pragma unroll
  for (int tt = 0; tt < CLEN; tt++) {
    size_t xi = (size_t)(b * TLEN + t0 + tt) * DI + d;
    float dtv = dtf[xi];
    float xv = b2f(*(const bf16t*)&xh[xi]) + b2f(*(const bf16t*)&xl[xi]);
    float dx = dtv * xv;
#pragma unroll
    for (int n = 0; n < NSTATE; n++) {
      float e = fexp2(dtv * A2[n]);
      st[n] = e * st[n] + dx * sB[tt][n];
      Pp[n] *= e;
    }
  }
  size_t base = ((size_t)(b * NCH + c) * NSTATE) * DI + d;
#pragma unroll
  for (int n = 0; n < NSTATE; n++) {
    P[base + (size_t)n * DI] = Pp[n];
    S[base + (size_t)n * DI] = st[n];
  }
}

// ---------------- scan pass 2: combine chunk boundaries; Sin written in-place into P
__global__ __launch_bounds__(256) void scan_pass2(
    float* __restrict__ P, const float* __restrict__ S, int nchunk)
{
  int idx = blockIdx.x * 256 + threadIdx.x;  // 0..32767 = (b, n, d)
  int d = idx & (DI - 1);
  int n = (idx >> 10) & (NSTATE - 1);
  int b = idx >> 14;
  float s = 0.f;
#pragma clang loop unroll_count(4)
  for (int c = 0; c < nchunk; c++) {
    size_t o = ((size_t)(b * nchunk + c) * NSTATE + n) * DI + d;
    float p = P[o], sv = S[o];
    P[o] = s;                 // Sin for chunk c
    s = p * s + sv;
  }
}

// ---------------- scan pass 3: full scan + D-skip + pre-silu'd gate -> y hi/lo
template <int CLEN>
__global__ __launch_bounds__(256) void scan_pass3(
    const float* __restrict__ dtf, const short* __restrict__ xh, const short* __restrict__ xl,
    const float* __restrict__ ssm, const void* __restrict__ alog,
    const float* __restrict__ Sin, const float* __restrict__ proj,
    const void* __restrict__ Dvec, short* __restrict__ yh, short* __restrict__ yl,
    const unsigned int* __restrict__ x0)
{
  constexpr int NCH = TLEN / CLEN;
  __shared__ float sBC[CLEN][2 * NSTATE];
  int f = detect_f(x0);
  int tid = threadIdx.x;
  int c = blockIdx.x % NCH;
  int r = blockIdx.x / NCH;
  int dblk = r & 3, b = r >> 2;
  int d = dblk * 256 + tid;
  int t0 = c * CLEN;
  for (int i = tid; i < CLEN * 2 * NSTATE; i += 256) {
    int rr = i >> 5, cc = i & 31;
    sBC[rr][cc] = ssm[(size_t)(b * TLEN + t0 + rr) * 64 + 32 + cc];
  }
  float A2[NSTATE], st[NSTATE];
  size_t base = ((size_t)(b * NCH + c) * NSTATE) * DI + d;
#pragma unroll
  for (int n = 0; n < NSTATE; n++) {
    A2[n] = -fexp2(load_any(alog, d * NSTATE + n, f) * LOG2E) * LOG2E;
    st[n] = Sin[base + (size_t)n * DI];
  }
  float Dd = load_any(Dvec, d, f);
  __syncthreads();
#pragma unroll
  for (int tt = 0; tt < CLEN; tt++) {
    int row = b * TLEN + t0 + tt;
    size_t xi = (size_t)row * DI + d;
    float dtv = dtf[xi];
    float xv = b2f(*(const bf16t*)&xh[xi]) + b2f(*(const bf16t*)&xl[xi]);
    float dx = dtv * xv;
    float yv = 0.f;
#pragma unroll
    for (int n = 0; n < NSTATE; n++) {
      float e = fexp2(dtv * A2[n]);
      st[n] = e * st[n] + dx * sBC[tt][n];
      yv += st[n] * sBC[tt][NSTATE + n];
    }
    float gs = proj[(size_t)row * 2048 + 1024 + d];   // silu already applied by conv
    float out = (yv + xv * Dd) * gs;
    bf16t h = f2b(out);
    yh[xi] = *(short*)&h;
    bf16t l = f2b(out - b2f(h));
    yl[xi] = *(short*)&l;
  }
}

extern "C" void kernel_launch(void* const* d_in, const int* in_sizes, int n_in,
                              void* d_out, int out_size, void* d_ws, size_t ws_size,
                              hipStream_t stream) {
  const void* x    = d_in[0];   // [2,2048,512]
  const void* w1   = d_in[1];   // [2048,512]
  const void* cw   = d_in[2];   // [1024,1,4]
  const void* cb   = d_in[3];   // [1024]
  const void* xw   = d_in[4];   // [64,1024]
  const void* dtw  = d_in[5];   // [1024,32]
  const void* dtb  = d_in[6];   // [1024]
  const void* alog = d_in[7];   // [1024,16]
  const void* Dv   = d_in[8];   // [1024]
  const void* w3   = d_in[9];   // [512,1024]
  const unsigned int* x0 = (const unsigned int*)x;

  char* ws = (char*)d_ws;
  float* proj = (float*)ws;            ws += (size_t)4096 * 2048 * 4;   // 33.55 MB
  short* xt_h = (short*)ws;            ws += (size_t)4096 * 1024 * 2;   // 8.39 MB
  short* xt_l = (short*)ws;            ws += (size_t)4096 * 1024 * 2;
  float* ssm  = (float*)ws;            ws += (size_t)4096 * 64 * 4;     // 1.05 MB
  short* y_h  = (short*)ws;            ws += (size_t)4096 * 1024 * 2;   // 8.39 MB
  short* y_l  = (short*)ws;            ws += (size_t)4096 * 1024 * 2;
  float* dtf  = (float*)ws;            ws += (size_t)4096 * 1024 * 4;   // 16.78 MB
  short* smH  = (short*)ws;            ws += (size_t)622592 * 2;        // 1.25 MB
  short* smL  = (short*)ws;            ws += (size_t)622592 * 2;
  short* sdH  = (short*)ws;            ws += (size_t)131072 * 2;        // 0.26 MB
  short* sdL  = (short*)ws;            ws += (size_t)131072 * 2;
  char*  R    = ws;                                                      // PS region / cast staging

  size_t fixed = (size_t)(ws - (char*)d_ws);
  int nchunk = 256;
  while (nchunk > 32) {
    size_t region = (size_t)262144 * nchunk;
    if (region < 12582912) region = 12582912;   // cast staging floor
    if (fixed + region <= ws_size) break;
    nchunk >>= 1;
  }
  int clen = TLEN / nchunk;

  short* bigH = (short*)R;                       // x @0, w1 @2097152 (hi/lo)
  short* bigL = (short*)(R + 6291456);
  float* P    = (float*)R;                       // after in_proj, region becomes P|S
  float* S    = (float*)(R + (size_t)131072 * nchunk);

  cast_hilo<<<dim3(3680), 256, 0, stream>>>(x, w1, xw, w3, dtw, bigH, bigL, smH, smL);
  // in_proj: [4096,512] x [2048,512]^T -> proj fp32 [4096,2048]
  gemm_split<128, 128, 0><<<dim3(32, 16), 256, 0, stream>>>(
      bigH, bigL, bigH + 2097152, bigL + 2097152, proj, 512, 512, 512, 2048,
      nullptr, x0, nullptr, nullptr);
  // depthwise conv + silu -> xt hi/lo; silu(gate) in place
  conv_silu<<<dim3(16384), 256, 0, stream>>>(proj, proj, cw, cb, xt_h, xt_l, x0);
  // x_proj: [4096,1024] x [64,1024]^T -> ssm fp32 [4096,64] + dt-slice hi/lo (fused)
  gemm_split<64, 64, 2><<<dim3(64, 1), 256, 0, stream>>>(
      xt_h, xt_l, smH, smL, ssm, 1024, 1024, 1024, 64, nullptr, x0, sdH, sdL);
  // dt: MFMA GEMM [4096,32] x [1024,32]^T + bias + softplus -> dtf
  gemm_split<64, 64, 1><<<dim3(64, 16), 256, 0, stream>>>(
      sdH, sdL, smH + 589824, smL + 589824, dtf, 32, 32, 32, 1024, dtb, x0,
      nullptr, nullptr);
  // chunked linear-recurrence scan -> y hi/lo
  dim3 sg(8 * nchunk);
  switch (clen) {
    case 8:
      scan_pass1<8><<<sg, 256, 0, stream>>>(dtf, xt_h, xt_l, ssm, alog, P, S, x0);
      scan_pass2<<<dim3(128), 256, 0, stream>>>(P, S, nchunk);
      scan_pass3<8><<<sg, 256, 0, stream>>>(dtf, xt_h, xt_l, ssm, alog, P, proj, Dv,
                                            y_h, y_l, x0);
      break;
    case 16:
      scan_pass1<16><<<sg, 256, 0, stream>>>(dtf, xt_h, xt_l, ssm, alog, P, S, x0);
      scan_pass2<<<dim3(128), 256, 0, stream>>>(P, S, nchunk);
      scan_pass3<16><<<sg, 256, 0, stream>>>(dtf, xt_h, xt_l, ssm, alog, P, proj, Dv,
                                             y_h, y_l, x0);
      break;
    case 32:
      scan_pass1<32><<<sg, 256, 0, stream>>>(dtf, xt_h, xt_l, ssm, alog, P, S, x0);
      scan_pass2<<<dim3(128), 256, 0, stream>>>(P, S, nchunk);
      scan_pass3<32><<<sg, 256, 0, stream>>>(dtf, xt_h, xt_l, ssm, alog, P, proj, Dv,
                                             y_h, y_l, x0);
      break;
    default:
      scan_pass1<64><<<sg, 256, 0, stream>>>(dtf, xt_h, xt_l, ssm, alog, P, S, x0);
      scan_pass2<<<dim3(128), 256, 0, stream>>>(P, S, nchunk);
      scan_pass3<64><<<sg, 256, 0, stream>>>(dtf, xt_h, xt_l, ssm, alog, P, proj, Dv,
                                             y_h, y_l, x0);
      break;
  }
  // out_proj: [4096,1024] x [512,1024]^T -> d_out fp32 [4096,512]
  gemm_split<64, 64, 0><<<dim3(64, 8), 256, 0, stream>>>(
      y_h, y_l, smH + 65536, smL + 65536, (float*)d_out, 1024, 1024, 1024, 512,
      nullptr, x0, nullptr, nullptr);
}

// Round 12
// 234.724 us; speedup vs baseline: 2.5305x; 1.1949x over previous
//
#include <hip/hip_runtime.h>
#include <hip/hip_bf16.h>
#include <math.h>

typedef __hip_bfloat16 bf16t;
typedef __attribute__((ext_vector_type(8))) short short8;
typedef __attribute__((ext_vector_type(4))) float f32x4;

#define DI 1024
#define NSTATE 16
#define TLEN 2048
#define LOG2E 1.4426950408889634f

__device__ __forceinline__ float b2f(bf16t v) { return __bfloat162float(v); }
__device__ __forceinline__ bf16t f2b(float v) { return __float2bfloat16(v); }
__device__ __forceinline__ float fexp2(float x) { return __builtin_amdgcn_exp2f(x); }
__device__ __forceinline__ float flog2(float x) { return __builtin_amdgcn_logf(x); }
__device__ __forceinline__ float softplus_fast(float v) {
  return (v > 20.f) ? v : flog2(1.f + fexp2(v * LOG2E)) * (1.f / LOG2E);
}

// wave-ballot dtype detect on first 64 words of x: 1 = fp32 inputs, 0 = bf16
__device__ __forceinline__ int detect_f(const unsigned int* __restrict__ x0) {
  unsigned int w = x0[threadIdx.x & 63];
  int e = (w >> 7) & 0xFF;
  unsigned long long m = __ballot(e >= 110 && e <= 135);
  return (__popcll(m) < 32) ? 1 : 0;
}

// runtime-dtype load for RAW INPUTS: f=1 -> fp32, f=0 -> bf16
__device__ __forceinline__ float load_any(const void* s, long i, int f) {
  return f ? ((const float*)s)[i] : b2f(((const bf16t*)s)[i]);
}

__device__ __forceinline__ void async16(const void* g, void* l) {
  __builtin_amdgcn_global_load_lds(
      (const __attribute__((address_space(1))) unsigned int*)g,
      (__attribute__((address_space(3))) unsigned int*)l, 16, 0, 0);
}

template <int N> __device__ __forceinline__ void waitcnt_vm() {
  if constexpr (N == 0)      asm volatile("s_waitcnt vmcnt(0)" ::: "memory");
  else if constexpr (N == 2) asm volatile("s_waitcnt vmcnt(2)" ::: "memory");
  else if constexpr (N == 4) asm volatile("s_waitcnt vmcnt(4)" ::: "memory");
  else if constexpr (N == 8) asm volatile("s_waitcnt vmcnt(8)" ::: "memory");
}
__device__ __forceinline__ void raw_barrier() { asm volatile("s_barrier" ::: "memory"); }

// ---------------- cast: x,w1 -> hi/lo pairs (big); xw,w3,dtw -> hi only (small)
// big: x[0,2097152) w1[2097152,3145728). small: xw[0,65536) w3[65536,589824) dtw[589824,622592)
__global__ __launch_bounds__(256) void cast_hilo(
    const void* __restrict__ x, const void* __restrict__ w1,
    const void* __restrict__ xw, const void* __restrict__ w3, const void* __restrict__ dtw,
    short* __restrict__ bigH, short* __restrict__ bigL, short* __restrict__ smallH)
{
  int f = detect_f((const unsigned int*)x);
  int i0 = (blockIdx.x * 256 + threadIdx.x) * 4;
#pragma unroll
  for (int q = 0; q < 4; q++) {
    int i = i0 + q;
    if (i >= 3768320) return;
    if (i < 3145728) {
      float v = (i < 2097152) ? load_any(x, i, f) : load_any(w1, i - 2097152, f);
      bf16t h = f2b(v);
      bigH[i] = *(short*)&h;
      bf16t l = f2b(v - b2f(h));
      bigL[i] = *(short*)&l;
    } else {
      int j = i - 3145728;
      float v;
      if (j < 65536)       v = load_any(xw, j, f);
      else if (j < 589824) v = load_any(w3, j - 65536, f);
      else                 v = load_any(dtw, j - 589824, f);
      bf16t h = f2b(v);
      smallH[j] = *(short*)&h;
    }
  }
}

// ---------------- bf16 MFMA GEMM, double-buffered K-loop
// SPLIT: C = Ah*Bh + Ah*Bl + Al*Bh (fp32-class).  !SPLIT: C = Ah*Bh.
// MODE 0: plain fp32 store. MODE 1: +bias softplus. MODE 2: fp32 + bf16 copy of cols<32.
template <int BM, int BN, int MODE, bool SPLIT>
__global__ __launch_bounds__(256) void gemm_mf(
    const short* __restrict__ Ah, const short* __restrict__ Al,
    const short* __restrict__ Bh, const short* __restrict__ Bl,
    float* __restrict__ C, int K, int lda, int ldb, int ldc,
    const void* __restrict__ bias, const unsigned int* __restrict__ x0,
    short* __restrict__ outH)
{
  constexpr int NFM = BM / 32, NFN = BN / 32;
  constexpr int SA = BM / 64, SB = BN / 64;
  constexpr int NL = (SPLIT ? 2 : 1) * (SA + SB);
  __shared__ __align__(16) short lAh[2 * BM * 32];
  __shared__ __align__(16) short lBh[2 * BN * 32];
  __shared__ __align__(16) short lAl[SPLIT ? 2 * BM * 32 : 4];
  __shared__ __align__(16) short lBl[SPLIT ? 2 * BN * 32 : 4];
  int tid = threadIdx.x;
  int lane = tid & 63, wave = tid >> 6;
  int bm = blockIdx.x * BM, bn = blockIdx.y * BN;
  int wm = (wave & 1) * (BM / 2), wn = (wave >> 1) * (BN / 2);
  f32x4 acc[NFM][NFN] = {};
  int r0 = tid >> 2, kp = (tid & 3) * 8;
  const short* pAh = Ah + (size_t)(bm + r0) * lda + kp;
  const short* pBh = Bh + (size_t)(bn + r0) * ldb + kp;
  const short* pAl = SPLIT ? Al + (size_t)(bm + r0) * lda + kp : nullptr;
  const short* pBl = SPLIT ? Bl + (size_t)(bn + r0) * ldb + kp : nullptr;
  int ldsOff = tid * 8;
  int la = (lane & 15) * 32 + (lane >> 4) * 8;
  int nIter = K / 32;

  auto stage = [&](int kk, int b) {
    int off = kk * 32;
    int bo = b * BM * 32;
#pragma unroll
    for (int s = 0; s < SA; s++) {
      async16(pAh + off + (size_t)s * 64 * lda, &lAh[bo + ldsOff + s * 64 * 32]);
      if constexpr (SPLIT)
        async16(pAl + off + (size_t)s * 64 * lda, &lAl[bo + ldsOff + s * 64 * 32]);
    }
    int bo2 = b * BN * 32;
#pragma unroll
    for (int s = 0; s < SB; s++) {
      async16(pBh + off + (size_t)s * 64 * ldb, &lBh[bo2 + ldsOff + s * 64 * 32]);
      if constexpr (SPLIT)
        async16(pBl + off + (size_t)s * 64 * ldb, &lBl[bo2 + ldsOff + s * 64 * 32]);
    }
  };

  stage(0, 0);
  for (int kk = 0; kk < nIter; kk++) {
    int cur = kk & 1;
    bool more = (kk + 1 < nIter);
    if (more) stage(kk + 1, cur ^ 1);
    if (more) waitcnt_vm<NL>(); else waitcnt_vm<0>();
    raw_barrier();
    short8 ah[NFM], al[NFM], bh[NFN], bl[NFN];
#pragma unroll
    for (int i = 0; i < NFM; i++) {
      ah[i] = *(const short8*)&lAh[cur * BM * 32 + (wm + i * 16) * 32 + la];
      if constexpr (SPLIT)
        al[i] = *(const short8*)&lAl[cur * BM * 32 + (wm + i * 16) * 32 + la];
    }
#pragma unroll
    for (int j = 0; j < NFN; j++) {
      bh[j] = *(const short8*)&lBh[cur * BN * 32 + (wn + j * 16) * 32 + la];
      if constexpr (SPLIT)
        bl[j] = *(const short8*)&lBl[cur * BN * 32 + (wn + j * 16) * 32 + la];
    }
#pragma unroll
    for (int i = 0; i < NFM; i++)
#pragma unroll
      for (int j = 0; j < NFN; j++) {
        acc[i][j] = __builtin_amdgcn_mfma_f32_16x16x32_bf16(ah[i], bh[j], acc[i][j], 0, 0, 0);
        if constexpr (SPLIT) {
          acc[i][j] = __builtin_amdgcn_mfma_f32_16x16x32_bf16(ah[i], bl[j], acc[i][j], 0, 0, 0);
          acc[i][j] = __builtin_amdgcn_mfma_f32_16x16x32_bf16(al[i], bh[j], acc[i][j], 0, 0, 0);
        }
      }
    raw_barrier();
  }
  int f = (MODE == 1) ? detect_f(x0) : 0;
  int rbase = (lane >> 4) * 4, ncol = lane & 15;
#pragma unroll
  for (int i = 0; i < NFM; i++)
#pragma unroll
    for (int j = 0; j < NFN; j++)
#pragma unroll
      for (int r = 0; r < 4; r++) {
        int m = bm + wm + i * 16 + rbase + r;
        int n = bn + wn + j * 16 + ncol;
        float v = acc[i][j][r];
        if (MODE == 1) v = softplus_fast(v + load_any(bias, n, f));
        C[(size_t)m * ldc + n] = v;
        if (MODE == 2 && n < 32) {
          bf16t h = f2b(v);
          outH[(size_t)m * 32 + n] = *(short*)&h;
        }
      }
}

// ---------------- depthwise causal conv(K=4)+SiLU -> xt bf16; silu(gate) -> gs bf16
__global__ __launch_bounds__(256) void conv_silu(
    const float* __restrict__ proj, const void* __restrict__ cw, const void* __restrict__ cb,
    short* __restrict__ xh, short* __restrict__ gs, const unsigned int* __restrict__ x0)
{
  int f = detect_f(x0);
  int idx = blockIdx.x * 256 + threadIdx.x;
  int d = idx & (DI - 1);
  int row = idx >> 10;
  int t = row & (TLEN - 1);
  float acc = load_any(cb, d, f);
#pragma unroll
  for (int k = 0; k < 4; k++) {
    int ts = t - 3 + k;
    if (ts >= 0) acc += load_any(cw, d * 4 + k, f) * proj[(size_t)(row - 3 + k) * 2048 + d];
  }
  float s = acc / (1.f + fexp2(-acc * LOG2E));
  bf16t h = f2b(s);
  xh[idx] = *(short*)&h;
  float g = proj[(size_t)row * 2048 + 1024 + d];
  float gsv = g / (1.f + fexp2(-g * LOG2E));
  bf16t gh = f2b(gsv);
  gs[idx] = *(short*)&gh;
}

// ---------------- scan pass 1: per-chunk transfer product P and local state S
template <int CLEN>
__global__ __launch_bounds__(256) void scan_pass1(
    const float* __restrict__ dtf, const short* __restrict__ xh,
    const float* __restrict__ ssm, const void* __restrict__ alog,
    float* __restrict__ P, float* __restrict__ S, const unsigned int* __restrict__ x0)
{
  constexpr int NCH = TLEN / CLEN;
  __shared__ float sB[CLEN][NSTATE];
  int f = detect_f(x0);
  int tid = threadIdx.x;
  int c = blockIdx.x % NCH;
  int r = blockIdx.x / NCH;
  int dblk = r & 3, b = r >> 2;
  int d = dblk * 256 + tid;
  int t0 = c * CLEN;
  for (int i = tid; i < CLEN * NSTATE; i += 256) {
    int rr = i >> 4, cc = i & 15;
    sB[rr][cc] = ssm[(size_t)(b * TLEN + t0 + rr) * 64 + 32 + cc];
  }
  float A2[NSTATE], st[NSTATE], Pp[NSTATE];
#pragma unroll
  for (int n = 0; n < NSTATE; n++) {
    A2[n] = -fexp2(load_any(alog, d * NSTATE + n, f) * LOG2E) * LOG2E;
    st[n] = 0.f; Pp[n] = 1.f;
  }
  __syncthreads();
#pragma unroll
  for (int tt = 0; tt < CLEN; tt++) {
    size_t xi = (size_t)(b * TLEN + t0 + tt) * DI + d;
    float dtv = dtf[xi];
    float xv = b2f(*(const bf16t*)&xh[xi]);
    float dx = dtv * xv;
#pragma unroll
    for (int n = 0; n < NSTATE; n++) {
      float e = fexp2(dtv * A2[n]);
      st[n] = e * st[n] + dx * sB[tt][n];
      Pp[n] *= e;
    }
  }
  size_t base = ((size_t)(b * NCH + c) * NSTATE) * DI + d;
#pragma unroll
  for (int n = 0; n < NSTATE; n++) {
    P[base + (size_t)n * DI] = Pp[n];
    S[base + (size_t)n * DI] = st[n];
  }
}

// ---------------- scan pass 2: combine chunk boundaries; Sin written in-place into P
__global__ __launch_bounds__(256) void scan_pass2(
    float* __restrict__ P, const float* __restrict__ S, int nchunk)
{
  int idx = blockIdx.x * 256 + threadIdx.x;  // 0..32767 = (b, n, d)
  int d = idx & (DI - 1);
  int n = (idx >> 10) & (NSTATE - 1);
  int b = idx >> 14;
  float s = 0.f;
#pragma clang loop unroll_count(4)
  for (int c = 0; c < nchunk; c++) {
    size_t o = ((size_t)(b * nchunk + c) * NSTATE + n) * DI + d;
    float p = P[o], sv = S[o];
    P[o] = s;                 // Sin for chunk c
    s = p * s + sv;
  }
}

// ---------------- scan pass 3: full scan + D-skip + pre-silu'd gate -> y bf16
template <int CLEN>
__global__ __launch_bounds__(256) void scan_pass3(
    const float* __restrict__ dtf, const short* __restrict__ xh,
    const float* __restrict__ ssm, const void* __restrict__ alog,
    const float* __restrict__ Sin, const short* __restrict__ gs,
    const void* __restrict__ Dvec, short* __restrict__ yh,
    const unsigned int* __restrict__ x0)
{
  constexpr int NCH = TLEN / CLEN;
  __shared__ float sBC[CLEN][2 * NSTATE];
  int f = detect_f(x0);
  int tid = threadIdx.x;
  int c = blockIdx.x % NCH;
  int r = blockIdx.x / NCH;
  int dblk = r & 3, b = r >> 2;
  int d = dblk * 256 + tid;
  int t0 = c * CLEN;
  for (int i = tid; i < CLEN * 2 * NSTATE; i += 256) {
    int rr = i >> 5, cc = i & 31;
    sBC[rr][cc] = ssm[(size_t)(b * TLEN + t0 + rr) * 64 + 32 + cc];
  }
  float A2[NSTATE], st[NSTATE];
  size_t base = ((size_t)(b * NCH + c) * NSTATE) * DI + d;
#pragma unroll
  for (int n = 0; n < NSTATE; n++) {
    A2[n] = -fexp2(load_any(alog, d * NSTATE + n, f) * LOG2E) * LOG2E;
    st[n] = Sin[base + (size_t)n * DI];
  }
  float Dd = load_any(Dvec, d, f);
  __syncthreads();
#pragma unroll
  for (int tt = 0; tt < CLEN; tt++) {
    int row = b * TLEN + t0 + tt;
    size_t xi = (size_t)row * DI + d;
    float dtv = dtf[xi];
    float xv = b2f(*(const bf16t*)&xh[xi]);
    float dx = dtv * xv;
    float yv = 0.f;
#pragma unroll
    for (int n = 0; n < NSTATE; n++) {
      float e = fexp2(dtv * A2[n]);
      st[n] = e * st[n] + dx * sBC[tt][n];
      yv += st[n] * sBC[tt][NSTATE + n];
    }
    float gsv = b2f(*(const bf16t*)&gs[xi]);
    float out = (yv + xv * Dd) * gsv;
    bf16t h = f2b(out);
    yh[xi] = *(short*)&h;
  }
}

extern "C" void kernel_launch(void* const* d_in, const int* in_sizes, int n_in,
                              void* d_out, int out_size, void* d_ws, size_t ws_size,
                              hipStream_t stream) {
  const void* x    = d_in[0];   // [2,2048,512]
  const void* w1   = d_in[1];   // [2048,512]
  const void* cw   = d_in[2];   // [1024,1,4]
  const void* cb   = d_in[3];   // [1024]
  const void* xw   = d_in[4];   // [64,1024]
  const void* dtw  = d_in[5];   // [1024,32]
  const void* dtb  = d_in[6];   // [1024]
  const void* alog = d_in[7];   // [1024,16]
  const void* Dv   = d_in[8];   // [1024]
  const void* w3   = d_in[9];   // [512,1024]
  const unsigned int* x0 = (const unsigned int*)x;

  char* ws = (char*)d_ws;
  float* proj = (float*)ws;            ws += (size_t)4096 * 2048 * 4;   // 33.55 MB
  short* xt_h = (short*)ws;            ws += (size_t)4096 * 1024 * 2;   // 8.39 MB
  short* gs_h = (short*)ws;            ws += (size_t)4096 * 1024 * 2;   // 8.39 MB
  float* ssm  = (float*)ws;            ws += (size_t)4096 * 64 * 4;     // 1.05 MB
  short* y_h  = (short*)ws;            ws += (size_t)4096 * 1024 * 2;   // 8.39 MB
  float* dtf  = (float*)ws;            ws += (size_t)4096 * 1024 * 4;   // 16.78 MB
  short* smH  = (short*)ws;            ws += (size_t)622592 * 2;        // 1.25 MB
  short* sdH  = (short*)ws;            ws += (size_t)131072 * 2;        // 0.26 MB
  char*  R    = ws;                                                      // staging / P|S

  size_t fixed = (size_t)(ws - (char*)d_ws);
  int nchunk = 128;   // CLEN=16: 1024 blocks for pass1/3, pass2 ~50 MB
  while (nchunk > 32) {
    size_t region = (size_t)262144 * nchunk;
    if (region < 12582912) region = 12582912;   // cast staging floor
    if (fixed + region <= ws_size) break;
    nchunk >>= 1;
  }
  int clen = TLEN / nchunk;

  short* bigH = (short*)R;                       // x @0, w1 @2097152 (hi/lo)
  short* bigL = (short*)(R + 6291456);
  float* P    = (float*)R;                       // after in_proj: P|S
  float* S    = (float*)(R + (size_t)131072 * nchunk);

  cast_hilo<<<dim3(3680), 256, 0, stream>>>(x, w1, xw, w3, dtw, bigH, bigL, smH);
  // in_proj (split, fp32-class): [4096,512] x [2048,512]^T -> proj fp32
  gemm_mf<128, 128, 0, true><<<dim3(32, 16), 256, 0, stream>>>(
      bigH, bigL, bigH + 2097152, bigL + 2097152, proj, 512, 512, 512, 2048,
      nullptr, x0, nullptr);
  // conv + silu -> xt bf16; silu(gate) -> gs bf16
  conv_silu<<<dim3(16384), 256, 0, stream>>>(proj, cw, cb, xt_h, gs_h, x0);
  // x_proj (plain bf16): [4096,1024] x [64,1024]^T -> ssm fp32 + dt-slice bf16
  gemm_mf<64, 64, 2, false><<<dim3(64, 1), 256, 0, stream>>>(
      xt_h, nullptr, smH, nullptr, ssm, 1024, 1024, 1024, 64, nullptr, x0, sdH);
  // dt (plain bf16): [4096,32] x [1024,32]^T + bias + softplus -> dtf fp32
  gemm_mf<64, 64, 1, false><<<dim3(64, 16), 256, 0, stream>>>(
      sdH, nullptr, smH + 589824, nullptr, dtf, 32, 32, 32, 1024, dtb, x0, nullptr);
  // chunked linear-recurrence scan -> y bf16
  dim3 sg(8 * nchunk);
  switch (clen) {
    case 16:
      scan_pass1<16><<<sg, 256, 0, stream>>>(dtf, xt_h, ssm, alog, P, S, x0);
      scan_pass2<<<dim3(128), 256, 0, stream>>>(P, S, nchunk);
      scan_pass3<16><<<sg, 256, 0, stream>>>(dtf, xt_h, ssm, alog, P, gs_h, Dv, y_h, x0);
      break;
    case 32:
      scan_pass1<32><<<sg, 256, 0, stream>>>(dtf, xt_h, ssm, alog, P, S, x0);
      scan_pass2<<<dim3(128), 256, 0, stream>>>(P, S, nchunk);
      scan_pass3<32><<<sg, 256, 0, stream>>>(dtf, xt_h, ssm, alog, P, gs_h, Dv, y_h, x0);
      break;
    default:
      scan_pass1<64><<<sg, 256, 0, stream>>>(dtf, xt_h, ssm, alog, P, S, x0);
      scan_pass2<<<dim3(128), 256, 0, stream>>>(P, S, nchunk);
      scan_pass3<64><<<sg, 256, 0, stream>>>(dtf, xt_h, ssm, alog, P, gs_h, Dv, y_h, x0);
      break;
  }
  // out_proj (plain bf16): [4096,1024] x [512,1024]^T -> d_out fp32
  gemm_mf<64, 64, 0, false><<<dim3(64, 8), 256, 0, stream>>>(
      y_h, nullptr, smH + 65536, nullptr, (float*)d_out, 1024, 1024, 1024, 512,
      nullptr, x0, nullptr);
}

// Round 13
// 222.900 us; speedup vs baseline: 2.6648x; 1.0530x over previous
//
#include <hip/hip_runtime.h>
#include <hip/hip_bf16.h>
#include <math.h>

typedef __hip_bfloat16 bf16t;
typedef __attribute__((ext_vector_type(8))) short short8;
typedef __attribute__((ext_vector_type(4))) float f32x4;

#define DI 1024
#define NSTATE 16
#define TLEN 2048
#define LOG2E 1.4426950408889634f

__device__ __forceinline__ float b2f(bf16t v) { return __bfloat162float(v); }
__device__ __forceinline__ bf16t f2b(float v) { return __float2bfloat16(v); }
__device__ __forceinline__ float fexp2(float x) { return __builtin_amdgcn_exp2f(x); }
__device__ __forceinline__ float flog2(float x) { return __builtin_amdgcn_logf(x); }
__device__ __forceinline__ float softplus_fast(float v) {
  return (v > 20.f) ? v : flog2(1.f + fexp2(v * LOG2E)) * (1.f / LOG2E);
}
__device__ __forceinline__ short bs(float v) { bf16t h = f2b(v); return *(short*)&h; }
__device__ __forceinline__ float sb(short v) { return b2f(*(bf16t*)&v); }

// wave-ballot dtype detect on first 64 words of x: 1 = fp32 inputs, 0 = bf16
__device__ __forceinline__ int detect_f(const unsigned int* __restrict__ x0) {
  unsigned int w = x0[threadIdx.x & 63];
  int e = (w >> 7) & 0xFF;
  unsigned long long m = __ballot(e >= 110 && e <= 135);
  return (__popcll(m) < 32) ? 1 : 0;
}

// runtime-dtype load for RAW INPUTS: f=1 -> fp32, f=0 -> bf16
__device__ __forceinline__ float load_any(const void* s, long i, int f) {
  return f ? ((const float*)s)[i] : b2f(((const bf16t*)s)[i]);
}

__device__ __forceinline__ void async16(const void* g, void* l) {
  __builtin_amdgcn_global_load_lds(
      (const __attribute__((address_space(1))) unsigned int*)g,
      (__attribute__((address_space(3))) unsigned int*)l, 16, 0, 0);
}

template <int N> __device__ __forceinline__ void waitcnt_vm() {
  if constexpr (N == 0)      asm volatile("s_waitcnt vmcnt(0)" ::: "memory");
  else if constexpr (N == 2) asm volatile("s_waitcnt vmcnt(2)" ::: "memory");
  else if constexpr (N == 4) asm volatile("s_waitcnt vmcnt(4)" ::: "memory");
}
__device__ __forceinline__ void raw_barrier() { asm volatile("s_barrier" ::: "memory"); }

// ---------------- bf16 cast of all 5 GEMM matrices (hi planes only)
// big (aliased over P/S): x[0,2097152) w1[2097152,3145728)
// small (persistent): xw[0,65536) w3[65536,589824) dtw[589824,622592)
__global__ __launch_bounds__(256) void cast_h(
    const void* __restrict__ x, const void* __restrict__ w1,
    const void* __restrict__ xw, const void* __restrict__ w3, const void* __restrict__ dtw,
    short* __restrict__ bigH, short* __restrict__ smallH)
{
  int f = detect_f((const unsigned int*)x);
  int i0 = (blockIdx.x * 256 + threadIdx.x) * 4;
#pragma unroll
  for (int q = 0; q < 4; q++) {
    int i = i0 + q;
    if (i >= 3768320) return;
    if (i < 3145728) {
      float v = (i < 2097152) ? load_any(x, i, f) : load_any(w1, i - 2097152, f);
      bigH[i] = bs(v);
    } else {
      int j = i - 3145728;
      float v;
      if (j < 65536)       v = load_any(xw, j, f);
      else if (j < 589824) v = load_any(w3, j - 65536, f);
      else                 v = load_any(dtw, j - 589824, f);
      smallH[j] = bs(v);
    }
  }
}

// ---------------- bf16 MFMA GEMM, double-buffered K-loop: C[M,N] = A[M,K] * B[N,K]^T
// MODE 0: fp32 C. MODE 1: +bias, softplus, bf16 store to outH. MODE 2: fp32 C + bf16 cols<32.
template <int BM, int BN, int MODE>
__global__ __launch_bounds__(256) void gemm_mf(
    const short* __restrict__ Ah, const short* __restrict__ Bh,
    float* __restrict__ C, int K, int lda, int ldb, int ldc,
    const void* __restrict__ bias, const unsigned int* __restrict__ x0,
    short* __restrict__ outH)
{
  constexpr int NFM = BM / 32, NFN = BN / 32;
  constexpr int SA = BM / 64, SB = BN / 64;
  constexpr int NL = SA + SB;
  __shared__ __align__(16) short lA[2 * BM * 32];
  __shared__ __align__(16) short lB[2 * BN * 32];
  int tid = threadIdx.x;
  int lane = tid & 63, wave = tid >> 6;
  int bm = blockIdx.x * BM, bn = blockIdx.y * BN;
  int wm = (wave & 1) * (BM / 2), wn = (wave >> 1) * (BN / 2);
  f32x4 acc[NFM][NFN] = {};
  int r0 = tid >> 2, kp = (tid & 3) * 8;
  const short* pA = Ah + (size_t)(bm + r0) * lda + kp;
  const short* pB = Bh + (size_t)(bn + r0) * ldb + kp;
  int ldsOff = tid * 8;
  int la = (lane & 15) * 32 + (lane >> 4) * 8;
  int nIter = K / 32;

  auto stage = [&](int kk, int b) {
    int off = kk * 32;
#pragma unroll
    for (int s = 0; s < SA; s++)
      async16(pA + off + (size_t)s * 64 * lda, &lA[b * BM * 32 + ldsOff + s * 64 * 32]);
#pragma unroll
    for (int s = 0; s < SB; s++)
      async16(pB + off + (size_t)s * 64 * ldb, &lB[b * BN * 32 + ldsOff + s * 64 * 32]);
  };

  stage(0, 0);
  for (int kk = 0; kk < nIter; kk++) {
    int cur = kk & 1;
    bool more = (kk + 1 < nIter);
    if (more) stage(kk + 1, cur ^ 1);
    if (more) waitcnt_vm<NL>(); else waitcnt_vm<0>();
    raw_barrier();
    short8 af[NFM], bf[NFN];
#pragma unroll
    for (int i = 0; i < NFM; i++)
      af[i] = *(const short8*)&lA[cur * BM * 32 + (wm + i * 16) * 32 + la];
#pragma unroll
    for (int j = 0; j < NFN; j++)
      bf[j] = *(const short8*)&lB[cur * BN * 32 + (wn + j * 16) * 32 + la];
#pragma unroll
    for (int i = 0; i < NFM; i++)
#pragma unroll
      for (int j = 0; j < NFN; j++)
        acc[i][j] = __builtin_amdgcn_mfma_f32_16x16x32_bf16(af[i], bf[j], acc[i][j], 0, 0, 0);
    raw_barrier();
  }
  int f = (MODE == 1) ? detect_f(x0) : 0;
  int rbase = (lane >> 4) * 4, ncol = lane & 15;
#pragma unroll
  for (int i = 0; i < NFM; i++)
#pragma unroll
    for (int j = 0; j < NFN; j++)
#pragma unroll
      for (int r = 0; r < 4; r++) {
        int m = bm + wm + i * 16 + rbase + r;
        int n = bn + wn + j * 16 + ncol;
        float v = acc[i][j][r];
        if constexpr (MODE == 1) {
          v = softplus_fast(v + load_any(bias, n, f));
          outH[(size_t)m * ldc + n] = bs(v);
        } else {
          C[(size_t)m * ldc + n] = v;
          if constexpr (MODE == 2) {
            if (n < 32) outH[(size_t)m * 32 + n] = bs(v);
          }
        }
      }
}

// ---------------- depthwise causal conv(K=4)+SiLU -> xt bf16; silu(gate) -> gs bf16
__global__ __launch_bounds__(256) void conv_silu(
    const float* __restrict__ proj, const void* __restrict__ cw, const void* __restrict__ cb,
    short* __restrict__ xh, short* __restrict__ gs, const unsigned int* __restrict__ x0)
{
  int f = detect_f(x0);
  int idx = blockIdx.x * 256 + threadIdx.x;
  int d = idx & (DI - 1);
  int row = idx >> 10;
  int t = row & (TLEN - 1);
  float acc = load_any(cb, d, f);
#pragma unroll
  for (int k = 0; k < 4; k++) {
    int ts = t - 3 + k;
    if (ts >= 0) acc += load_any(cw, d * 4 + k, f) * proj[(size_t)(row - 3 + k) * 2048 + d];
  }
  float s = acc / (1.f + fexp2(-acc * LOG2E));
  xh[idx] = bs(s);
  float g = proj[(size_t)row * 2048 + 1024 + d];
  gs[idx] = bs(g / (1.f + fexp2(-g * LOG2E)));
}

// ---------------- scan pass 1: per-chunk transfer product P and local state S (bf16)
template <int CLEN>
__global__ __launch_bounds__(256) void scan_pass1(
    const short* __restrict__ dtf, const short* __restrict__ xh,
    const float* __restrict__ ssm, const void* __restrict__ alog,
    short* __restrict__ P, short* __restrict__ S, const unsigned int* __restrict__ x0)
{
  constexpr int NCH = TLEN / CLEN;
  __shared__ float sB[CLEN][NSTATE];
  int f = detect_f(x0);
  int tid = threadIdx.x;
  int c = blockIdx.x % NCH;
  int r = blockIdx.x / NCH;
  int dblk = r & 3, b = r >> 2;
  int d = dblk * 256 + tid;
  int t0 = c * CLEN;
  for (int i = tid; i < CLEN * NSTATE; i += 256) {
    int rr = i >> 4, cc = i & 15;
    sB[rr][cc] = ssm[(size_t)(b * TLEN + t0 + rr) * 64 + 32 + cc];
  }
  float A2[NSTATE], st[NSTATE], Pp[NSTATE];
#pragma unroll
  for (int n = 0; n < NSTATE; n++) {
    A2[n] = -fexp2(load_any(alog, d * NSTATE + n, f) * LOG2E) * LOG2E;
    st[n] = 0.f; Pp[n] = 1.f;
  }
  __syncthreads();
#pragma unroll
  for (int tt = 0; tt < CLEN; tt++) {
    size_t xi = (size_t)(b * TLEN + t0 + tt) * DI + d;
    float dtv = sb(dtf[xi]);
    float xv = sb(xh[xi]);
    float dx = dtv * xv;
#pragma unroll
    for (int n = 0; n < NSTATE; n++) {
      float e = fexp2(dtv * A2[n]);
      st[n] = e * st[n] + dx * sB[tt][n];
      Pp[n] *= e;
    }
  }
  size_t base = ((size_t)(b * NCH + c) * NSTATE) * DI + d;
#pragma unroll
  for (int n = 0; n < NSTATE; n++) {
    P[base + (size_t)n * DI] = bs(Pp[n]);
    S[base + (size_t)n * DI] = bs(st[n]);
  }
}

// ---------------- scan pass 2: combine chunk boundaries; Sin in-place into P (bf16)
__global__ __launch_bounds__(64) void scan_pass2(
    short* __restrict__ P, const short* __restrict__ S, int nchunk)
{
  int idx = blockIdx.x * 64 + threadIdx.x;  // 0..32767 = (b, n, d)
  int d = idx & (DI - 1);
  int n = (idx >> 10) & (NSTATE - 1);
  int b = idx >> 14;
  float s = 0.f;
#pragma clang loop unroll_count(4)
  for (int c = 0; c < nchunk; c++) {
    size_t o = ((size_t)(b * nchunk + c) * NSTATE + n) * DI + d;
    float p = sb(P[o]), sv = sb(S[o]);
    P[o] = bs(s);             // Sin for chunk c
    s = p * s + sv;
  }
}

// ---------------- scan pass 3: full scan + D-skip + pre-silu'd gate -> y bf16
template <int CLEN>
__global__ __launch_bounds__(256) void scan_pass3(
    const short* __restrict__ dtf, const short* __restrict__ xh,
    const float* __restrict__ ssm, const void* __restrict__ alog,
    const short* __restrict__ Sin, const short* __restrict__ gs,
    const void* __restrict__ Dvec, short* __restrict__ yh,
    const unsigned int* __restrict__ x0)
{
  constexpr int NCH = TLEN / CLEN;
  __shared__ float sBC[CLEN][2 * NSTATE];
  int f = detect_f(x0);
  int tid = threadIdx.x;
  int c = blockIdx.x % NCH;
  int r = blockIdx.x / NCH;
  int dblk = r & 3, b = r >> 2;
  int d = dblk * 256 + tid;
  int t0 = c * CLEN;
  for (int i = tid; i < CLEN * 2 * NSTATE; i += 256) {
    int rr = i >> 5, cc = i & 31;
    sBC[rr][cc] = ssm[(size_t)(b * TLEN + t0 + rr) * 64 + 32 + cc];
  }
  float A2[NSTATE], st[NSTATE];
  size_t base = ((size_t)(b * NCH + c) * NSTATE) * DI + d;
#pragma unroll
  for (int n = 0; n < NSTATE; n++) {
    A2[n] = -fexp2(load_any(alog, d * NSTATE + n, f) * LOG2E) * LOG2E;
    st[n] = sb(Sin[base + (size_t)n * DI]);
  }
  float Dd = load_any(Dvec, d, f);
  __syncthreads();
#pragma unroll
  for (int tt = 0; tt < CLEN; tt++) {
    int row = b * TLEN + t0 + tt;
    size_t xi = (size_t)row * DI + d;
    float dtv = sb(dtf[xi]);
    float xv = sb(xh[xi]);
    float dx = dtv * xv;
    float yv = 0.f;
#pragma unroll
    for (int n = 0; n < NSTATE; n++) {
      float e = fexp2(dtv * A2[n]);
      st[n] = e * st[n] + dx * sBC[tt][n];
      yv += st[n] * sBC[tt][NSTATE + n];
    }
    float out = (yv + xv * Dd) * sb(gs[xi]);
    yh[xi] = bs(out);
  }
}

extern "C" void kernel_launch(void* const* d_in, const int* in_sizes, int n_in,
                              void* d_out, int out_size, void* d_ws, size_t ws_size,
                              hipStream_t stream) {
  const void* x    = d_in[0];   // [2,2048,512]
  const void* w1   = d_in[1];   // [2048,512]
  const void* cw   = d_in[2];   // [1024,1,4]
  const void* cb   = d_in[3];   // [1024]
  const void* xw   = d_in[4];   // [64,1024]
  const void* dtw  = d_in[5];   // [1024,32]
  const void* dtb  = d_in[6];   // [1024]
  const void* alog = d_in[7];   // [1024,16]
  const void* Dv   = d_in[8];   // [1024]
  const void* w3   = d_in[9];   // [512,1024]
  const unsigned int* x0 = (const unsigned int*)x;

  char* ws = (char*)d_ws;
  float* proj = (float*)ws;            ws += (size_t)4096 * 2048 * 4;   // 33.55 MB
  short* xt_h = (short*)ws;            ws += (size_t)4096 * 1024 * 2;   // 8.39 MB
  short* gs_h = (short*)ws;            ws += (size_t)4096 * 1024 * 2;   // 8.39 MB
  float* ssm  = (float*)ws;            ws += (size_t)4096 * 64 * 4;     // 1.05 MB
  short* y_h  = (short*)ws;            ws += (size_t)4096 * 1024 * 2;   // 8.39 MB
  short* dtf  = (short*)ws;            ws += (size_t)4096 * 1024 * 2;   // 8.39 MB
  short* smH  = (short*)ws;            ws += (size_t)622592 * 2;        // 1.25 MB
  short* sdH  = (short*)ws;            ws += (size_t)131072 * 2;        // 0.26 MB
  char*  R    = ws;                                                      // staging / P|S

  size_t fixed = (size_t)(ws - (char*)d_ws);
  int nchunk = 128;   // CLEN=16: 1024 blocks for pass1/3; P/S bf16
  while (nchunk > 32) {
    size_t region = (size_t)131072 * nchunk;      // P+S bf16
    if (region < 7536640) region = 7536640;       // cast staging floor (hi planes)
    if (fixed + region <= ws_size) break;
    nchunk >>= 1;
  }
  int clen = TLEN / nchunk;

  short* bigH = (short*)R;                       // x @0, w1 @2097152 (hi)
  short* P    = (short*)R;                       // after in_proj: P|S (bf16)
  short* S    = (short*)(R + (size_t)65536 * nchunk);

  cast_h<<<dim3(3680), 256, 0, stream>>>(x, w1, xw, w3, dtw, bigH, smH);
  // in_proj (plain bf16): [4096,512] x [2048,512]^T -> proj fp32
  gemm_mf<128, 128, 0><<<dim3(32, 16), 256, 0, stream>>>(
      bigH, bigH + 2097152, proj, 512, 512, 512, 2048, nullptr, x0, nullptr);
  // conv + silu -> xt bf16; silu(gate) -> gs bf16
  conv_silu<<<dim3(16384), 256, 0, stream>>>(proj, cw, cb, xt_h, gs_h, x0);
  // x_proj: [4096,1024] x [64,1024]^T -> ssm fp32 + dt-slice bf16
  gemm_mf<64, 64, 2><<<dim3(64, 1), 256, 0, stream>>>(
      xt_h, smH, ssm, 1024, 1024, 1024, 64, nullptr, x0, sdH);
  // dt: [4096,32] x [1024,32]^T + bias + softplus -> dtf bf16
  gemm_mf<64, 64, 1><<<dim3(64, 16), 256, 0, stream>>>(
      sdH, smH + 589824, nullptr, 32, 32, 32, 1024, dtb, x0, dtf);
  // chunked linear-recurrence scan -> y bf16
  dim3 sg(8 * nchunk);
  switch (clen) {
    case 16:
      scan_pass1<16><<<sg, 256, 0, stream>>>(dtf, xt_h, ssm, alog, P, S, x0);
      scan_pass2<<<dim3(512), 64, 0, stream>>>(P, S, nchunk);
      scan_pass3<16><<<sg, 256, 0, stream>>>(dtf, xt_h, ssm, alog, P, gs_h, Dv, y_h, x0);
      break;
    case 32:
      scan_pass1<32><<<sg, 256, 0, stream>>>(dtf, xt_h, ssm, alog, P, S, x0);
      scan_pass2<<<dim3(512), 64, 0, stream>>>(P, S, nchunk);
      scan_pass3<32><<<sg, 256, 0, stream>>>(dtf, xt_h, ssm, alog, P, gs_h, Dv, y_h, x0);
      break;
    default:
      scan_pass1<64><<<sg, 256, 0, stream>>>(dtf, xt_h, ssm, alog, P, S, x0);
      scan_pass2<<<dim3(512), 64, 0, stream>>>(P, S, nchunk);
      scan_pass3<64><<<sg, 256, 0, stream>>>(dtf, xt_h, ssm, alog, P, gs_h, Dv, y_h, x0);
      break;
  }
  // out_proj: [4096,1024] x [512,1024]^T -> d_out fp32
  gemm_mf<64, 64, 0><<<dim3(64, 8), 256, 0, stream>>>(
      y_h, smH + 65536, (float*)d_out, 1024, 1024, 1024, 512, nullptr, x0, nullptr);
}

// Round 14
// 221.120 us; speedup vs baseline: 2.6862x; 1.0080x over previous
//
#include <hip/hip_runtime.h>
#include <hip/hip_bf16.h>
#include <math.h>

typedef __hip_bfloat16 bf16t;
typedef __attribute__((ext_vector_type(8))) short short8;
typedef __attribute__((ext_vector_type(4))) float f32x4;

#define DI 1024
#define NSTATE 16
#define TLEN 2048
#define LOG2E 1.4426950408889634f

__device__ __forceinline__ float b2f(bf16t v) { return __bfloat162float(v); }
__device__ __forceinline__ bf16t f2b(float v) { return __float2bfloat16(v); }
__device__ __forceinline__ float fexp2(float x) { return __builtin_amdgcn_exp2f(x); }
__device__ __forceinline__ float flog2(float x) { return __builtin_amdgcn_logf(x); }
__device__ __forceinline__ float softplus_fast(float v) {
  return (v > 20.f) ? v : flog2(1.f + fexp2(v * LOG2E)) * (1.f / LOG2E);
}
__device__ __forceinline__ short bs(float v) { bf16t h = f2b(v); return *(short*)&h; }
__device__ __forceinline__ float sb(short v) { return b2f(*(bf16t*)&v); }

// wave-ballot dtype detect on first 64 words of x: 1 = fp32 inputs, 0 = bf16
__device__ __forceinline__ int detect_f(const unsigned int* __restrict__ x0) {
  unsigned int w = x0[threadIdx.x & 63];
  int e = (w >> 7) & 0xFF;
  unsigned long long m = __ballot(e >= 110 && e <= 135);
  return (__popcll(m) < 32) ? 1 : 0;
}

// runtime-dtype load for RAW INPUTS: f=1 -> fp32, f=0 -> bf16
__device__ __forceinline__ float load_any(const void* s, long i, int f) {
  return f ? ((const float*)s)[i] : b2f(((const bf16t*)s)[i]);
}

__device__ __forceinline__ void async16(const void* g, void* l) {
  __builtin_amdgcn_global_load_lds(
      (const __attribute__((address_space(1))) unsigned int*)g,
      (__attribute__((address_space(3))) unsigned int*)l, 16, 0, 0);
}

template <int N> __device__ __forceinline__ void waitcnt_vm() {
  if constexpr (N == 0)      asm volatile("s_waitcnt vmcnt(0)" ::: "memory");
  else if constexpr (N == 2) asm volatile("s_waitcnt vmcnt(2)" ::: "memory");
  else if constexpr (N == 4) asm volatile("s_waitcnt vmcnt(4)" ::: "memory");
}
__device__ __forceinline__ void raw_barrier() { asm volatile("s_barrier" ::: "memory"); }

// ---------------- bf16 cast of all 5 GEMM matrices (hi planes only)
// big (aliased over P/S): x[0,2097152) w1[2097152,3145728)
// small (persistent): xw[0,65536) w3[65536,589824) dtw[589824,622592)
__global__ __launch_bounds__(256) void cast_h(
    const void* __restrict__ x, const void* __restrict__ w1,
    const void* __restrict__ xw, const void* __restrict__ w3, const void* __restrict__ dtw,
    short* __restrict__ bigH, short* __restrict__ smallH)
{
  int f = detect_f((const unsigned int*)x);
  int i0 = (blockIdx.x * 256 + threadIdx.x) * 4;
#pragma unroll
  for (int q = 0; q < 4; q++) {
    int i = i0 + q;
    if (i >= 3768320) return;
    if (i < 3145728) {
      float v = (i < 2097152) ? load_any(x, i, f) : load_any(w1, i - 2097152, f);
      bigH[i] = bs(v);
    } else {
      int j = i - 3145728;
      float v;
      if (j < 65536)       v = load_any(xw, j, f);
      else if (j < 589824) v = load_any(w3, j - 65536, f);
      else                 v = load_any(dtw, j - 589824, f);
      smallH[j] = bs(v);
    }
  }
}

// ---------------- bf16 MFMA GEMM, double-buffered K-loop: C[M,N] = A[M,K] * B[N,K]^T
// MODE 0: fp32 C. MODE 1: +bias softplus -> bf16 outH. MODE 2: fp32 C + bf16 cols<32.
// MODE 3 (in_proj): cols<1024 -> bf16 outH (raw); cols>=1024 -> silu -> bf16 out2.
template <int BM, int BN, int MODE>
__global__ __launch_bounds__(256) void gemm_mf(
    const short* __restrict__ Ah, const short* __restrict__ Bh,
    float* __restrict__ C, int K, int lda, int ldb, int ldc,
    const void* __restrict__ bias, const unsigned int* __restrict__ x0,
    short* __restrict__ outH, short* __restrict__ out2)
{
  constexpr int NFM = BM / 32, NFN = BN / 32;
  constexpr int SA = BM / 64, SB = BN / 64;
  constexpr int NL = SA + SB;
  __shared__ __align__(16) short lA[2 * BM * 32];
  __shared__ __align__(16) short lB[2 * BN * 32];
  int tid = threadIdx.x;
  int lane = tid & 63, wave = tid >> 6;
  int bm = blockIdx.x * BM, bn = blockIdx.y * BN;
  int wm = (wave & 1) * (BM / 2), wn = (wave >> 1) * (BN / 2);
  f32x4 acc[NFM][NFN] = {};
  int r0 = tid >> 2, kp = (tid & 3) * 8;
  const short* pA = Ah + (size_t)(bm + r0) * lda + kp;
  const short* pB = Bh + (size_t)(bn + r0) * ldb + kp;
  int ldsOff = tid * 8;
  int la = (lane & 15) * 32 + (lane >> 4) * 8;
  int nIter = K / 32;

  auto stage = [&](int kk, int b) {
    int off = kk * 32;
#pragma unroll
    for (int s = 0; s < SA; s++)
      async16(pA + off + (size_t)s * 64 * lda, &lA[b * BM * 32 + ldsOff + s * 64 * 32]);
#pragma unroll
    for (int s = 0; s < SB; s++)
      async16(pB + off + (size_t)s * 64 * ldb, &lB[b * BN * 32 + ldsOff + s * 64 * 32]);
  };

  stage(0, 0);
  for (int kk = 0; kk < nIter; kk++) {
    int cur = kk & 1;
    bool more = (kk + 1 < nIter);
    if (more) stage(kk + 1, cur ^ 1);
    if (more) waitcnt_vm<NL>(); else waitcnt_vm<0>();
    raw_barrier();
    short8 af[NFM], bf[NFN];
#pragma unroll
    for (int i = 0; i < NFM; i++)
      af[i] = *(const short8*)&lA[cur * BM * 32 + (wm + i * 16) * 32 + la];
#pragma unroll
    for (int j = 0; j < NFN; j++)
      bf[j] = *(const short8*)&lB[cur * BN * 32 + (wn + j * 16) * 32 + la];
#pragma unroll
    for (int i = 0; i < NFM; i++)
#pragma unroll
      for (int j = 0; j < NFN; j++)
        acc[i][j] = __builtin_amdgcn_mfma_f32_16x16x32_bf16(af[i], bf[j], acc[i][j], 0, 0, 0);
    raw_barrier();
  }
  int f = (MODE == 1) ? detect_f(x0) : 0;
  int rbase = (lane >> 4) * 4, ncol = lane & 15;
#pragma unroll
  for (int i = 0; i < NFM; i++)
#pragma unroll
    for (int j = 0; j < NFN; j++)
#pragma unroll
      for (int r = 0; r < 4; r++) {
        int m = bm + wm + i * 16 + rbase + r;
        int n = bn + wn + j * 16 + ncol;
        float v = acc[i][j][r];
        if constexpr (MODE == 1) {
          v = softplus_fast(v + load_any(bias, n, f));
          outH[(size_t)m * ldc + n] = bs(v);
        } else if constexpr (MODE == 3) {
          if (n < 1024) {
            outH[(size_t)m * 1024 + n] = bs(v);                       // raw x half
          } else {
            float gv = v / (1.f + fexp2(-v * LOG2E));                 // silu(gate)
            out2[(size_t)m * 1024 + (n - 1024)] = bs(gv);
          }
        } else {
          C[(size_t)m * ldc + n] = v;
          if constexpr (MODE == 2) {
            if (n < 32) outH[(size_t)m * 32 + n] = bs(v);
          }
        }
      }
}

// ---------------- depthwise causal conv(K=4)+SiLU over bf16 xraw -> xt bf16
__global__ __launch_bounds__(256) void conv_silu(
    const short* __restrict__ xraw, const void* __restrict__ cw, const void* __restrict__ cb,
    short* __restrict__ xh, const unsigned int* __restrict__ x0)
{
  int f = detect_f(x0);
  int idx = blockIdx.x * 256 + threadIdx.x;
  int d = idx & (DI - 1);
  int row = idx >> 10;
  int t = row & (TLEN - 1);
  float acc = load_any(cb, d, f);
#pragma unroll
  for (int k = 0; k < 4; k++) {
    int ts = t - 3 + k;
    if (ts >= 0) acc += load_any(cw, d * 4 + k, f) * sb(xraw[(size_t)(row - 3 + k) * 1024 + d]);
  }
  float s = acc / (1.f + fexp2(-acc * LOG2E));
  xh[idx] = bs(s);
}

// ---------------- scan pass 1: per-chunk transfer product P and local state S (bf16)
template <int CLEN>
__global__ __launch_bounds__(256) void scan_pass1(
    const short* __restrict__ dtf, const short* __restrict__ xh,
    const float* __restrict__ ssm, const void* __restrict__ alog,
    short* __restrict__ P, short* __restrict__ S, const unsigned int* __restrict__ x0)
{
  constexpr int NCH = TLEN / CLEN;
  __shared__ float sB[CLEN][NSTATE];
  int f = detect_f(x0);
  int tid = threadIdx.x;
  int c = blockIdx.x % NCH;
  int r = blockIdx.x / NCH;
  int dblk = r & 3, b = r >> 2;
  int d = dblk * 256 + tid;
  int t0 = c * CLEN;
  for (int i = tid; i < CLEN * NSTATE; i += 256) {
    int rr = i >> 4, cc = i & 15;
    sB[rr][cc] = ssm[(size_t)(b * TLEN + t0 + rr) * 64 + 32 + cc];
  }
  float A2[NSTATE], st[NSTATE], Pp[NSTATE];
#pragma unroll
  for (int n = 0; n < NSTATE; n++) {
    A2[n] = -fexp2(load_any(alog, d * NSTATE + n, f) * LOG2E) * LOG2E;
    st[n] = 0.f; Pp[n] = 1.f;
  }
  __syncthreads();
#pragma unroll
  for (int tt = 0; tt < CLEN; tt++) {
    size_t xi = (size_t)(b * TLEN + t0 + tt) * DI + d;
    float dtv = sb(dtf[xi]);
    float xv = sb(xh[xi]);
    float dx = dtv * xv;
#pragma unroll
    for (int n = 0; n < NSTATE; n++) {
      float e = fexp2(dtv * A2[n]);
      st[n] = e * st[n] + dx * sB[tt][n];
      Pp[n] *= e;
    }
  }
  size_t base = ((size_t)(b * NCH + c) * NSTATE) * DI + d;
#pragma unroll
  for (int n = 0; n < NSTATE; n++) {
    P[base + (size_t)n * DI] = bs(Pp[n]);
    S[base + (size_t)n * DI] = bs(st[n]);
  }
}

// ---------------- scan pass 2: combine chunk boundaries; Sin in-place into P (bf16)
__global__ __launch_bounds__(64) void scan_pass2(
    short* __restrict__ P, const short* __restrict__ S, int nchunk)
{
  int idx = blockIdx.x * 64 + threadIdx.x;  // 0..32767 = (b, n, d)
  int d = idx & (DI - 1);
  int n = (idx >> 10) & (NSTATE - 1);
  int b = idx >> 14;
  float s = 0.f;
#pragma clang loop unroll_count(4)
  for (int c = 0; c < nchunk; c++) {
    size_t o = ((size_t)(b * nchunk + c) * NSTATE + n) * DI + d;
    float p = sb(P[o]), sv = sb(S[o]);
    P[o] = bs(s);             // Sin for chunk c
    s = p * s + sv;
  }
}

// ---------------- scan pass 3: full scan + D-skip + pre-silu'd gate -> y bf16
template <int CLEN>
__global__ __launch_bounds__(256) void scan_pass3(
    const short* __restrict__ dtf, const short* __restrict__ xh,
    const float* __restrict__ ssm, const void* __restrict__ alog,
    const short* __restrict__ Sin, const short* __restrict__ gs,
    const void* __restrict__ Dvec, short* __restrict__ yh,
    const unsigned int* __restrict__ x0)
{
  constexpr int NCH = TLEN / CLEN;
  __shared__ float sBC[CLEN][2 * NSTATE];
  int f = detect_f(x0);
  int tid = threadIdx.x;
  int c = blockIdx.x % NCH;
  int r = blockIdx.x / NCH;
  int dblk = r & 3, b = r >> 2;
  int d = dblk * 256 + tid;
  int t0 = c * CLEN;
  for (int i = tid; i < CLEN * 2 * NSTATE; i += 256) {
    int rr = i >> 5, cc = i & 31;
    sBC[rr][cc] = ssm[(size_t)(b * TLEN + t0 + rr) * 64 + 32 + cc];
  }
  float A2[NSTATE], st[NSTATE];
  size_t base = ((size_t)(b * NCH + c) * NSTATE) * DI + d;
#pragma unroll
  for (int n = 0; n < NSTATE; n++) {
    A2[n] = -fexp2(load_any(alog, d * NSTATE + n, f) * LOG2E) * LOG2E;
    st[n] = sb(Sin[base + (size_t)n * DI]);
  }
  float Dd = load_any(Dvec, d, f);
  __syncthreads();
#pragma unroll
  for (int tt = 0; tt < CLEN; tt++) {
    int row = b * TLEN + t0 + tt;
    size_t xi = (size_t)row * DI + d;
    float dtv = sb(dtf[xi]);
    float xv = sb(xh[xi]);
    float dx = dtv * xv;
    float yv = 0.f;
#pragma unroll
    for (int n = 0; n < NSTATE; n++) {
      float e = fexp2(dtv * A2[n]);
      st[n] = e * st[n] + dx * sBC[tt][n];
      yv += st[n] * sBC[tt][NSTATE + n];
    }
    float out = (yv + xv * Dd) * sb(gs[xi]);
    yh[xi] = bs(out);
  }
}

extern "C" void kernel_launch(void* const* d_in, const int* in_sizes, int n_in,
                              void* d_out, int out_size, void* d_ws, size_t ws_size,
                              hipStream_t stream) {
  const void* x    = d_in[0];   // [2,2048,512]
  const void* w1   = d_in[1];   // [2048,512]
  const void* cw   = d_in[2];   // [1024,1,4]
  const void* cb   = d_in[3];   // [1024]
  const void* xw   = d_in[4];   // [64,1024]
  const void* dtw  = d_in[5];   // [1024,32]
  const void* dtb  = d_in[6];   // [1024]
  const void* alog = d_in[7];   // [1024,16]
  const void* Dv   = d_in[8];   // [1024]
  const void* w3   = d_in[9];   // [512,1024]
  const unsigned int* x0 = (const unsigned int*)x;

  char* ws = (char*)d_ws;
  short* xraw = (short*)ws;            ws += (size_t)4096 * 1024 * 2;   // 8.39 MB
  short* gs_h = (short*)ws;            ws += (size_t)4096 * 1024 * 2;   // 8.39 MB
  short* xt_h = (short*)ws;            ws += (size_t)4096 * 1024 * 2;   // 8.39 MB
  float* ssm  = (float*)ws;            ws += (size_t)4096 * 64 * 4;     // 1.05 MB
  short* y_h  = (short*)ws;            ws += (size_t)4096 * 1024 * 2;   // 8.39 MB
  short* dtf  = (short*)ws;            ws += (size_t)4096 * 1024 * 2;   // 8.39 MB
  short* smH  = (short*)ws;            ws += (size_t)622592 * 2;        // 1.25 MB
  short* sdH  = (short*)ws;            ws += (size_t)131072 * 2;        // 0.26 MB
  char*  R    = ws;                                                      // staging / P|S

  size_t fixed = (size_t)(ws - (char*)d_ws);
  int nchunk = 64;    // CLEN=32: 512 blocks for pass1/3; pass2 chain 64 iters
  while (nchunk > 32) {
    size_t region = (size_t)131072 * nchunk;      // P+S bf16
    if (region < 7536640) region = 7536640;       // cast staging floor
    if (fixed + region <= ws_size) break;
    nchunk >>= 1;
  }
  int clen = TLEN / nchunk;

  short* bigH = (short*)R;                       // x @0, w1 @2097152 (hi)
  short* P    = (short*)R;                       // after in_proj: P|S (bf16)
  short* S    = (short*)(R + (size_t)65536 * nchunk);

  cast_h<<<dim3(3680), 256, 0, stream>>>(x, w1, xw, w3, dtw, bigH, smH);
  // in_proj: [4096,512] x [2048,512]^T -> xraw bf16 + silu(gate) bf16 (MODE 3)
  gemm_mf<128, 128, 3><<<dim3(32, 16), 256, 0, stream>>>(
      bigH, bigH + 2097152, nullptr, 512, 512, 512, 2048, nullptr, x0, xraw, gs_h);
  // conv + silu -> xt bf16
  conv_silu<<<dim3(16384), 256, 0, stream>>>(xraw, cw, cb, xt_h, x0);
  // x_proj: [4096,1024] x [64,1024]^T -> ssm fp32 + dt-slice bf16
  gemm_mf<64, 64, 2><<<dim3(64, 1), 256, 0, stream>>>(
      xt_h, smH, ssm, 1024, 1024, 1024, 64, nullptr, x0, sdH, nullptr);
  // dt: [4096,32] x [1024,32]^T + bias + softplus -> dtf bf16
  gemm_mf<64, 64, 1><<<dim3(64, 16), 256, 0, stream>>>(
      sdH, smH + 589824, nullptr, 32, 32, 32, 1024, dtb, x0, dtf, nullptr);
  // chunked linear-recurrence scan -> y bf16
  dim3 sg(8 * nchunk);
  switch (clen) {
    case 16:
      scan_pass1<16><<<sg, 256, 0, stream>>>(dtf, xt_h, ssm, alog, P, S, x0);
      scan_pass2<<<dim3(512), 64, 0, stream>>>(P, S, nchunk);
      scan_pass3<16><<<sg, 256, 0, stream>>>(dtf, xt_h, ssm, alog, P, gs_h, Dv, y_h, x0);
      break;
    case 32:
      scan_pass1<32><<<sg, 256, 0, stream>>>(dtf, xt_h, ssm, alog, P, S, x0);
      scan_pass2<<<dim3(512), 64, 0, stream>>>(P, S, nchunk);
      scan_pass3<32><<<sg, 256, 0, stream>>>(dtf, xt_h, ssm, alog, P, gs_h, Dv, y_h, x0);
      break;
    default:
      scan_pass1<64><<<sg, 256, 0, stream>>>(dtf, xt_h, ssm, alog, P, S, x0);
      scan_pass2<<<dim3(512), 64, 0, stream>>>(P, S, nchunk);
      scan_pass3<64><<<sg, 256, 0, stream>>>(dtf, xt_h, ssm, alog, P, gs_h, Dv, y_h, x0);
      break;
  }
  // out_proj: [4096,1024] x [512,1024]^T -> d_out fp32
  gemm_mf<64, 64, 0><<<dim3(64, 8), 256, 0, stream>>>(
      y_h, smH + 65536, (float*)d_out, 1024, 1024, 1024, 512, nullptr, x0, nullptr, nullptr);
}